// Round 10
// baseline (1931.206 us; speedup 1.0000x reference)
//
#include <hip/hip_runtime.h>
#include <hip/hip_bf16.h>
#include <math.h>

#define NN 100000
#define NE 640000
#define NB 2000

typedef __attribute__((ext_vector_type(4))) float v4f;
typedef long long ll64;
#define MFMA8(a, b, c) __builtin_amdgcn_mfma_f32_16x16x32_fp8_fp8(a, b, c, 0, 0, 0)

// scales: activations x16, weights x256, accum de-scale 1/4096
#define INV_S 0.000244140625f
#define ASCL 16.0f
#define AINV 0.0625f

#if __has_builtin(__builtin_amdgcn_cvt_pk_fp8_f32) && __has_builtin(__builtin_amdgcn_cvt_f32_fp8)
#define HW_FP8 1
#else
#define HW_FP8 0
#endif

// ---------- int32/int64 index handling --------------------------------------
__device__ __forceinline__ int IDX(const void* p, size_t i, int is64) {
    return is64 ? (int)((const long long*)p)[i] : ((const int*)p)[i];
}
__device__ __forceinline__ int clampi(int v, int n) {
    return ((unsigned)v < (unsigned)n) ? v : 0;
}

__global__ void k_detect(const int* bn32, int* flag) {
    if (threadIdx.x == 0 && blockIdx.x == 0) {
        int is64 = 1;
        for (int k = 50001; k < 50401; k += 2)
            if (bn32[k] != 0) { is64 = 0; break; }
        *flag = is64;
    }
}

// ---------- fp8 e4m3 codec: HW cvt on gfx950, software fallback -------------
__device__ __forceinline__ unsigned sw_enc_fp8(float x) {
    unsigned s = (__float_as_uint(x) >> 24) & 0x80u;
    float ax = fminf(fabsf(x), 448.f);
    if (ax < 0.015625f) {
        unsigned m = (unsigned)(ax * 512.f + 0.5f);
        return s | m;
    }
    unsigned b = __float_as_uint(ax) + 0x00080000u;
    unsigned e = (b >> 23) - 120u;
    unsigned m = (b >> 20) & 7u;
    unsigned v = (e << 3) | m;
    if (v > 0x7Eu) v = 0x7Eu;
    return s | v;
}
__device__ __forceinline__ float sw_dec_fp8(unsigned b) {
    unsigned s = (b & 0x80u) << 24;
    unsigned e = (b >> 3) & 15u;
    unsigned m = b & 7u;
    if (e) return __uint_as_float(s | ((e + 120u) << 23) | (m << 20));
    float f = (float)m * 0.001953125f;
    return (b & 0x80u) ? -f : f;
}
__device__ __forceinline__ unsigned enc1(float x) {
#if HW_FP8
    return (unsigned)__builtin_amdgcn_cvt_pk_fp8_f32(x, x, 0, false) & 255u;
#else
    return sw_enc_fp8(x);
#endif
}
__device__ __forceinline__ unsigned encpk(float a, float b) {
#if HW_FP8
    return (unsigned)__builtin_amdgcn_cvt_pk_fp8_f32(a, b, 0, false) & 0xFFFFu;
#else
    return sw_enc_fp8(a) | (sw_enc_fp8(b) << 8);
#endif
}
__device__ __forceinline__ float dec1(unsigned b) {
#if HW_FP8
    return __builtin_amdgcn_cvt_f32_fp8((int)b, 0);
#else
    return sw_dec_fp8(b);
#endif
}
__device__ __forceinline__ float bf_f(unsigned short u) {
    return __uint_as_float((unsigned)u << 16);
}
__device__ __forceinline__ unsigned short f_to_bf(float x) {
    __hip_bfloat16 h = __float2bfloat16(x);
    return *(unsigned short*)&h;
}

// ---------- node type embed -------------------------------------------------
__global__ __launch_bounds__(256) void k_node_embed(const float* __restrict__ h_node,
                                                    const float* __restrict__ W,
                                                    unsigned char* __restrict__ hn8) {
    __shared__ float sh[8][16];
    int t = threadIdx.x;
    int r0 = blockIdx.x * 8;
    if (t < 128) sh[t >> 4][t & 15] = h_node[r0 * 16 + t];
    float w[16];
#pragma unroll
    for (int k = 0; k < 16; ++k) w[k] = W[k * 256 + t];
    __syncthreads();
#pragma unroll
    for (int r = 0; r < 8; ++r) {
        float acc = 0.f;
#pragma unroll
        for (int k = 0; k < 16; ++k) acc += sh[r][k] * w[k];
        hn8[(size_t)(r0 + r) * 256 + t] = (unsigned char)enc1(ASCL * acc);
    }
}

// ---------- edge type embed: write he8 in dst-sorted slot order -------------
__global__ __launch_bounds__(256) void k_edge_embed(const float* __restrict__ h_edge,
                                                    const float* __restrict__ W,
                                                    const int* __restrict__ perm,
                                                    unsigned char* __restrict__ he8) {
    __shared__ float sh[16][5];
    int t = threadIdx.x;
    int e0 = blockIdx.x * 16;
    if (t < 80) {
        int row = t / 5, col = t % 5;
        int e = perm[e0 + row];
        sh[row][col] = h_edge[(size_t)e * 5 + col];
    }
    int c = t & 127;
    int es = t >> 7;
    float w[5];
#pragma unroll
    for (int k = 0; k < 5; ++k) w[k] = W[k * 128 + c];
    __syncthreads();
#pragma unroll
    for (int e = 0; e < 8; ++e) {
        int ee = es * 8 + e;
        float acc = 0.f;
#pragma unroll
        for (int k = 0; k < 5; ++k) acc += sh[ee][k] * w[k];
        he8[(size_t)(e0 + ee) * 128 + c] = (unsigned char)enc1(ASCL * acc);
    }
}

// ---------- weight transposes (fp8, x256) -----------------------------------
__global__ __launch_bounds__(256) void k_tr_w1(const float* __restrict__ W,
                                               unsigned char* __restrict__ WT) {
    int i = blockIdx.x * 256 + threadIdx.x;
    if (i >= 3 * 128 * 128) return;
    int l = i / 16384, r = i % 16384;
    int n = r / 128, k = r % 128;
    WT[i] = (unsigned char)enc1(256.f * W[(size_t)l * 641 * 128 + (size_t)k * 128 + n]);
}
__global__ __launch_bounds__(256) void k_tr_w2(const float* __restrict__ W,
                                               unsigned char* __restrict__ WT) {
    int i = blockIdx.x * 256 + threadIdx.x;
    if (i >= 3 * 256 * 128) return;
    int l = i / 32768, r = i % 32768;
    int n = r / 128, k = r % 128;
    WT[i] = (unsigned char)enc1(256.f * W[(size_t)l * 384 * 256 + (size_t)(256 + k) * 256 + n]);
}
__global__ __launch_bounds__(256) void k_tr_nu(const float* __restrict__ W,
                                               unsigned char* __restrict__ WT) {
    int i = blockIdx.x * 256 + threadIdx.x;
    if (i >= 3 * 256 * 512) return;
    int l = i / 131072, r = i % 131072;
    int n = r / 512, k = r % 512;
    WT[i] = (unsigned char)enc1(256.f * W[(size_t)l * 512 * 256 + (size_t)k * 256 + n]);
}
// WpreT[l][n][k] n<512,k<256 : [Psrc | Pdst | Q] weight blocks
__global__ __launch_bounds__(256) void k_tr_pre(const float* __restrict__ Weu,
                                                const float* __restrict__ Wmsg,
                                                unsigned char* __restrict__ WT) {
    int i = blockIdx.x * 256 + threadIdx.x;
    if (i >= 3 * 512 * 256) return;
    int l = i / 131072, r = i % 131072;
    int n = r / 256, k = r % 256;
    float w;
    if (n < 128)      w = Weu[(size_t)l * 641 * 128 + (size_t)(128 + k) * 128 + n];
    else if (n < 256) w = Weu[(size_t)l * 641 * 128 + (size_t)(384 + k) * 128 + (n - 128)];
    else              w = Wmsg[(size_t)l * 384 * 256 + (size_t)k * 256 + (n - 256)];
    WT[i] = (unsigned char)enc1(256.f * w);
}

// ---------- dst-sorted edge permutation (built once) ------------------------
__global__ __launch_bounds__(256) void k_hist(const void* __restrict__ ei,
                                              const int* __restrict__ flag,
                                              int* __restrict__ hist) {
    int e = blockIdx.x * 256 + threadIdx.x;
    if (e >= NE) return;
    int d = clampi(IDX(ei, (size_t)NE + e, *flag), NN);
    atomicAdd(&hist[d], 1);
}
__global__ __launch_bounds__(1024) void k_scan(const int* __restrict__ hist,
                                               int* __restrict__ rowptr) {
    __shared__ int part[1024];
    int t = threadIdx.x;
    const int C = 98;
    int s = 0;
    for (int j = 0; j < C; ++j) {
        int i = t * C + j;
        if (i < NN) s += hist[i];
    }
    part[t] = s;
    __syncthreads();
    if (t == 0) {
        int run = 0;
        for (int i = 0; i < 1024; ++i) { int v = part[i]; part[i] = run; run += v; }
    }
    __syncthreads();
    int run = part[t];
    for (int j = 0; j < C; ++j) {
        int i = t * C + j;
        if (i < NN) { rowptr[i] = run; run += hist[i]; }
    }
}
// perm + permuted src/dst/dist + inverse map
__global__ __launch_bounds__(256) void k_perm(const void* __restrict__ ei,
                                              const int* __restrict__ flag,
                                              const float* __restrict__ pos,
                                              int* __restrict__ cursor,
                                              int* __restrict__ perm,
                                              int* __restrict__ inv,
                                              int* __restrict__ srcs,
                                              int* __restrict__ dsts,
                                              float* __restrict__ dist_s) {
    int e = blockIdx.x * 256 + threadIdx.x;
    if (e >= NE) return;
    int is64 = *flag;
    int s = clampi(IDX(ei, (size_t)e, is64), NN);
    int d = clampi(IDX(ei, (size_t)NE + e, is64), NN);
    int p = atomicAdd(&cursor[d], 1);
    perm[p] = e;
    inv[e] = p;
    srcs[p] = s;
    dsts[p] = d;
    float dx = pos[d * 3 + 0] - pos[s * 3 + 0];
    float dy = pos[d * 3 + 1] - pos[s * 3 + 1];
    float dz = pos[d * 3 + 2] - pos[s * 3 + 2];
    dist_s[p] = sqrtf(dx * dx + dy * dy + dz * dz);
}

// ---------- node-side precompute: R = [Psrc|Pdst|Q] = hn @ WpreT ------------
#define NP_AS 264
__global__ __launch_bounds__(256, 3) void k_node_pre(
    const unsigned char* __restrict__ hn8, const unsigned char* __restrict__ WpreT,
    unsigned char* __restrict__ R) {
    __shared__ unsigned char s_A[64 * NP_AS];
    int t = threadIdx.x;
    int rb = blockIdx.x * 64;
    {
        int row = t >> 2, sb = t & 3;
        int gr = rb + row; if (gr >= NN) gr = NN - 1;
        const uint4* sp = (const uint4*)(hn8 + (size_t)gr * 256 + sb * 64);
        uint4 a = sp[0], b = sp[1], c = sp[2], d = sp[3];
        uint4* dp = (uint4*)&s_A[row * NP_AS + sb * 64];
        dp[0] = a; dp[1] = b; dp[2] = c; dp[3] = d;
    }
    __syncthreads();
    int lane = t & 63, wv = t >> 6, quad = lane >> 4, l16 = lane & 15;
    v4f zero4 = {0.f, 0.f, 0.f, 0.f};
#pragma unroll
    for (int pass = 0; pass < 2; ++pass) {
        int nt0 = wv * 8 + pass * 4;
        v4f acc[4][4];
#pragma unroll
        for (int mt = 0; mt < 4; ++mt)
#pragma unroll
            for (int nl = 0; nl < 4; ++nl) acc[mt][nl] = zero4;
#pragma unroll 2
        for (int k = 0; k < 256; k += 32) {
            int ko = k + quad * 8;
            ll64 b[4];
#pragma unroll
            for (int nl = 0; nl < 4; ++nl)
                b[nl] = *(const ll64*)(WpreT + (size_t)((nt0 + nl) * 16 + l16) * 256 + ko);
#pragma unroll
            for (int mt = 0; mt < 4; ++mt) {
                ll64 a = *(const ll64*)&s_A[(mt * 16 + l16) * NP_AS + ko];
#pragma unroll
                for (int nl = 0; nl < 4; ++nl) acc[mt][nl] = MFMA8(a, b[nl], acc[mt][nl]);
            }
        }
#pragma unroll
        for (int nl = 0; nl < 4; ++nl) {
            int c = (nt0 + nl) * 16 + l16;
#pragma unroll
            for (int mt = 0; mt < 4; ++mt)
#pragma unroll
                for (int rr = 0; rr < 2; ++rr) {
                    int rw0 = mt * 16 + quad * 4 + rr * 2;
                    unsigned pk = encpk(acc[mt][nl][rr * 2] * 0.00390625f,
                                        acc[mt][nl][rr * 2 + 1] * 0.00390625f);
                    if (rb + rw0 < NN)
                        R[(size_t)(rb + rw0) * 512 + c] = (unsigned char)(pk & 255u);
                    if (rb + rw0 + 1 < NN)
                        R[(size_t)(rb + rw0 + 1) * 512 + c] = (unsigned char)(pk >> 8);
                }
        }
    }
}

// ---------- fused edge+msg kernel: 32 sorted edges/block, 4 waves -----------
#define EF_S 136   // he/Ps/Pd/s_h row stride (bytes)
#define EF_QS 264  // Q row stride (bytes)
#define EF_MS 264  // s_msg row stride (shorts)
__global__ __launch_bounds__(256, 4) void k_edge_fused(
    unsigned char* __restrict__ he8, const unsigned char* __restrict__ R,
    const float* __restrict__ dist_s,
    const int* __restrict__ srcs, const int* __restrict__ dsts,
    const unsigned char* __restrict__ W1T, const float* __restrict__ W_eu,
    const float* __restrict__ b_eu,
    const unsigned char* __restrict__ W2T, const float* __restrict__ b_msg,
    unsigned short* __restrict__ agg) {
    __shared__ __align__(16) unsigned char s_A[32 * EF_S];    // he
    __shared__ __align__(16) unsigned char s_Pd[32 * EF_S];
    __shared__ __align__(16) unsigned char s_Ph[32 * EF_S];   // Ps then he_new
    __shared__ __align__(16) unsigned char s_Q[32 * EF_QS];
    __shared__ __align__(16) unsigned short s_msg[32 * EF_MS];
    __shared__ float s_dist[32];
    __shared__ int s_dsti[32];
    int t = threadIdx.x;
    int eb = blockIdx.x * 32;
    int row = t >> 3, sb = t & 7;
    int sid = srcs[eb + row];
    int did = dsts[eb + row];
    if (t < 32) {
        s_dsti[t] = dsts[eb + t];
        s_dist[t] = dist_s[eb + t];
    }
    *(uint4*)&s_A[row * EF_S + sb * 16] =
        *(const uint4*)(he8 + (size_t)(eb + row) * 128 + sb * 16);
    *(uint4*)&s_Ph[row * EF_S + sb * 16] =
        *(const uint4*)(R + (size_t)sid * 512 + sb * 16);
    *(uint4*)&s_Pd[row * EF_S + sb * 16] =
        *(const uint4*)(R + (size_t)did * 512 + 128 + sb * 16);
    {
        const uint4* qp = (const uint4*)(R + (size_t)sid * 512 + 256 + sb * 32);
        uint4 q0 = qp[0], q1 = qp[1];
        *(uint4*)&s_Q[row * EF_QS + sb * 32] = q0;
        *(uint4*)&s_Q[row * EF_QS + sb * 32 + 16] = q1;
    }
    int lane = t & 63, wv = t >> 6, quad = lane >> 4, l16 = lane & 15;
    int n0 = wv * 2;
    const unsigned char* B0 = W1T + (size_t)(n0 * 16 + l16) * 128 + quad * 8;
    ll64 Brg[4][2];
#pragma unroll
    for (int kk = 0; kk < 4; ++kk) {
        Brg[kk][0] = *(const ll64*)(B0 + kk * 32);
        Brg[kk][1] = *(const ll64*)(B0 + 2048 + kk * 32);
    }
    __syncthreads();

    v4f zero4 = {0.f, 0.f, 0.f, 0.f};
    // ---- edge GEMM: 2 M-tiles x 2 N-tiles, K=128 ----
    v4f acc[2][2];
    acc[0][0] = zero4; acc[0][1] = zero4; acc[1][0] = zero4; acc[1][1] = zero4;
#pragma unroll
    for (int kk = 0; kk < 4; ++kk) {
        int ko = kk * 32 + quad * 8;
#pragma unroll
        for (int mt = 0; mt < 2; ++mt) {
            ll64 a = *(const ll64*)&s_A[(mt * 16 + l16) * EF_S + ko];
            acc[mt][0] = MFMA8(a, Brg[kk][0], acc[mt][0]);
            acc[mt][1] = MFMA8(a, Brg[kk][1], acc[mt][1]);
        }
    }
    // ---- edge epilogue (paired HW fp8 encode) ----
#pragma unroll
    for (int nl = 0; nl < 2; ++nl) {
        int c = (n0 + nl) * 16 + l16;
        float w640 = W_eu[640 * 128 + c];
        float bb = b_eu[c];
#pragma unroll
        for (int mt = 0; mt < 2; ++mt)
#pragma unroll
            for (int rr = 0; rr < 2; ++rr) {
                int rw0 = mt * 16 + quad * 4 + rr * 2;
                int rw1 = rw0 + 1;
                float S0 = (dec1(s_Ph[rw0 * EF_S + c]) +
                            dec1(s_Pd[rw0 * EF_S + c])) * AINV;
                float S1 = (dec1(s_Ph[rw1 * EF_S + c]) +
                            dec1(s_Pd[rw1 * EF_S + c])) * AINV;
                float v0 = fmaxf(acc[mt][nl][rr * 2] * INV_S + S0 +
                                 s_dist[rw0] * w640 + bb, 0.f);
                float v1 = fmaxf(acc[mt][nl][rr * 2 + 1] * INV_S + S1 +
                                 s_dist[rw1] * w640 + bb, 0.f);
                unsigned pk = encpk(ASCL * v0, ASCL * v1);
                unsigned char q0 = (unsigned char)(pk & 255u);
                unsigned char q1 = (unsigned char)(pk >> 8);
                s_Ph[rw0 * EF_S + c] = q0;
                s_Ph[rw1 * EF_S + c] = q1;
                he8[(size_t)(eb + rw0) * 128 + c] = q0;
                he8[(size_t)(eb + rw1) * 128 + c] = q1;
            }
    }
    __syncthreads();

    // ---- msg GEMM: 2 M-tiles x 4 N-tiles, K=128 over he_new ----
    v4f mac[2][4];
#pragma unroll
    for (int nl = 0; nl < 4; ++nl) { mac[0][nl] = zero4; mac[1][nl] = zero4; }
    int q0n = wv * 4;
#pragma unroll
    for (int kk = 0; kk < 4; ++kk) {
        int ko = kk * 32 + quad * 8;
        ll64 b[4];
#pragma unroll
        for (int nl = 0; nl < 4; ++nl)
            b[nl] = *(const ll64*)(W2T + (size_t)((q0n + nl) * 16 + l16) * 128 + ko);
#pragma unroll
        for (int mt = 0; mt < 2; ++mt) {
            ll64 a = *(const ll64*)&s_Ph[(mt * 16 + l16) * EF_S + ko];
#pragma unroll
            for (int nl = 0; nl < 4; ++nl) mac[mt][nl] = MFMA8(a, b[nl], mac[mt][nl]);
        }
    }
    // ---- msg epilogue: + Q + bias, relu -> bf16 into s_msg ----
#pragma unroll
    for (int nl = 0; nl < 4; ++nl) {
        int c = (q0n + nl) * 16 + l16;
        float bm = b_msg[c];
#pragma unroll
        for (int mt = 0; mt < 2; ++mt)
#pragma unroll
            for (int r = 0; r < 4; ++r) {
                int rw = mt * 16 + quad * 4 + r;
                float qv = dec1(s_Q[rw * EF_QS + c]) * AINV;
                float v = fmaxf(mac[mt][nl][r] * INV_S + qv + bm, 0.f);
                s_msg[rw * EF_MS + c] = f_to_bf(v);
            }
    }
    __syncthreads();
    // ---- run-merged packed bf16 atomics (dst sorted within block) ----
    {
        int cp = t & 127;      // column pair
        int half = t >> 7;     // rows 0..15 or 16..31
        int r0 = half * 16, r1 = r0 + 16;
        float ax = 0.f, ay = 0.f;
        int cur = s_dsti[r0];
        for (int rw = r0; rw < r1; ++rw) {
            int d2 = s_dsti[rw];
            if (d2 != cur) {
                if (ax != 0.f || ay != 0.f) {
                    __hip_bfloat162 pv;
                    pv.x = __float2bfloat16(ax);
                    pv.y = __float2bfloat16(ay);
                    unsafeAtomicAdd((__hip_bfloat162*)&agg[(size_t)cur * 256 + cp * 2], pv);
                }
                ax = 0.f; ay = 0.f; cur = d2;
            }
            unsigned v = *(const unsigned*)&s_msg[rw * EF_MS + cp * 2];
            ax += bf_f((unsigned short)(v & 0xFFFFu));
            ay += bf_f((unsigned short)(v >> 16));
        }
        if (ax != 0.f || ay != 0.f) {
            __hip_bfloat162 pv;
            pv.x = __float2bfloat16(ax);
            pv.y = __float2bfloat16(ay);
            unsafeAtomicAdd((__hip_bfloat162*)&agg[(size_t)cur * 256 + cp * 2], pv);
        }
    }
}

// ---------- node update: hn += relu([hn|agg]@W_nu + b) ----------------------
#define NL_AS 520
__global__ __launch_bounds__(256, 3) void k_node_layer(
    unsigned char* __restrict__ hn8, const unsigned short* __restrict__ agg,
    const unsigned char* __restrict__ WnuT, const float* __restrict__ b) {
    __shared__ unsigned char s_A[64 * NL_AS];
    int t = threadIdx.x;
    int rb = blockIdx.x * 64;
    {
        int row = t >> 2, sb = t & 3;
        int gr = rb + row; if (gr >= NN) gr = NN - 1;
        const uint4* sp = (const uint4*)(hn8 + (size_t)gr * 256 + sb * 64);
        uint4 a = sp[0], b2 = sp[1], c = sp[2], d = sp[3];
        uint4* dp = (uint4*)&s_A[row * NL_AS + sb * 64];
        dp[0] = a; dp[1] = b2; dp[2] = c; dp[3] = d;
        const unsigned short* ap = agg + (size_t)gr * 256 + sb * 64;
        unsigned char* dq = &s_A[row * NL_AS + 256 + sb * 64];
#pragma unroll
        for (int j = 0; j < 64; j += 2) {
            unsigned pk = encpk(ASCL * bf_f(ap[j]), ASCL * bf_f(ap[j + 1]));
            *(unsigned short*)&dq[j] = (unsigned short)pk;
        }
    }
    __syncthreads();
    int lane = t & 63, wv = t >> 6, quad = lane >> 4, l16 = lane & 15;
    v4f zero4 = {0.f, 0.f, 0.f, 0.f};
    v4f acc[4][4];
#pragma unroll
    for (int mt = 0; mt < 4; ++mt)
#pragma unroll
        for (int nl = 0; nl < 4; ++nl) acc[mt][nl] = zero4;
    int q0 = wv * 4;
#pragma unroll 2
    for (int k = 0; k < 512; k += 32) {
        int ko = k + quad * 8;
        ll64 b2[4];
#pragma unroll
        for (int nl = 0; nl < 4; ++nl)
            b2[nl] = *(const ll64*)(WnuT + (size_t)((q0 + nl) * 16 + l16) * 512 + ko);
#pragma unroll
        for (int mt = 0; mt < 4; ++mt) {
            ll64 a = *(const ll64*)&s_A[(mt * 16 + l16) * NL_AS + ko];
#pragma unroll
            for (int nl = 0; nl < 4; ++nl) acc[mt][nl] = MFMA8(a, b2[nl], acc[mt][nl]);
        }
    }
#pragma unroll
    for (int nl = 0; nl < 4; ++nl) {
        int c = (q0 + nl) * 16 + l16;
        float bv = b[c];
#pragma unroll
        for (int mt = 0; mt < 4; ++mt)
#pragma unroll
            for (int rr = 0; rr < 2; ++rr) {
                int rw0 = mt * 16 + quad * 4 + rr * 2;
                float o0 = dec1(s_A[rw0 * NL_AS + c]) * AINV;
                float o1 = dec1(s_A[(rw0 + 1) * NL_AS + c]) * AINV;
                float v0 = o0 + fmaxf(acc[mt][nl][rr * 2] * INV_S + bv, 0.f);
                float v1 = o1 + fmaxf(acc[mt][nl][rr * 2 + 1] * INV_S + bv, 0.f);
                unsigned pk = encpk(ASCL * v0, ASCL * v1);
                if (rb + rw0 < NN)
                    hn8[(size_t)(rb + rw0) * 256 + c] = (unsigned char)(pk & 255u);
                if (rb + rw0 + 1 < NN)
                    hn8[(size_t)(rb + rw0 + 1) * 256 + c] = (unsigned char)(pk >> 8);
            }
    }
}

// ---------- pooling + final MLP --------------------------------------------
__device__ __forceinline__ int lbound(const void* a, int n, int v, int is64) {
    int lo = 0, hi = n;
    while (lo < hi) {
        int mid = (lo + hi) >> 1;
        if (IDX(a, mid, is64) < v) lo = mid + 1; else hi = mid;
    }
    return lo;
}

__global__ __launch_bounds__(512) void k_pool_mlp(
    const unsigned char* __restrict__ hn8, const unsigned char* __restrict__ he8,
    const int* __restrict__ inv,
    const void* __restrict__ bn, const void* __restrict__ be,
    const int* __restrict__ flag,
    const float* __restrict__ Wf1, const float* __restrict__ bf1,
    const float* __restrict__ Wf2, const float* __restrict__ bf2,
    float* __restrict__ out) {
    __shared__ float s_sub[384];
    __shared__ float s_hid[512];
    int b = blockIdx.x;
    int t = threadIdx.x;
    int is64 = *flag;
    if (t < 256) {
        int lo = lbound(bn, NN, b, is64), hi = lbound(bn, NN, b + 1, is64);
        float s = 0.f;
        for (int i = lo; i < hi; ++i) s += dec1(hn8[(size_t)i * 256 + t]);
        s_sub[t] = s * AINV / fmaxf((float)(hi - lo), 1.f);
    } else if (t < 384) {
        int c = t - 256;
        int lo = lbound(be, NE, b, is64), hi = lbound(be, NE, b + 1, is64);
        float s = 0.f;
        for (int i = lo; i < hi; ++i)
            s += dec1(he8[(size_t)inv[i] * 128 + c]);
        s_sub[256 + c] = s * AINV / fmaxf((float)(hi - lo), 1.f);
    }
    __syncthreads();
    float hacc = bf1[t];
    for (int k = 0; k < 384; ++k) hacc += s_sub[k] * Wf1[k * 512 + t];
    s_hid[t] = fmaxf(hacc, 0.f);
    __syncthreads();
    if (t < 256) {
        float o = bf2[t];
        for (int k = 0; k < 512; ++k) o += s_hid[k] * Wf2[k * 256 + t];
        out[(size_t)b * 256 + t] = o;
    }
}

// ---------- second output ---------------------------------------------------
__global__ __launch_bounds__(256) void k_write_batch(const void* __restrict__ bn,
                                                     const int* __restrict__ flag,
                                                     float* __restrict__ out) {
    int i = blockIdx.x * 256 + threadIdx.x;
    if (i < NN) out[(size_t)NB * 256 + i] = (float)IDX(bn, i, *flag);
}

__global__ __launch_bounds__(256) void k_fill(float* __restrict__ p, int n, float v) {
    int i = blockIdx.x * 256 + threadIdx.x;
    if (i < n) p[i] = v;
}

extern "C" void kernel_launch(void* const* d_in, const int* in_sizes, int n_in,
                              void* d_out, int out_size, void* d_ws, size_t ws_size,
                              hipStream_t stream) {
    const float* h_node = (const float*)d_in[0];
    const float* pos    = (const float*)d_in[1];
    const float* h_edge = (const float*)d_in[2];
    const float* W_node = (const float*)d_in[3];
    const float* W_edge = (const float*)d_in[4];
    const float* W_eu   = (const float*)d_in[5];
    const float* b_eu   = (const float*)d_in[6];
    const float* W_msg  = (const float*)d_in[7];
    const float* b_msg  = (const float*)d_in[8];
    const float* W_nu   = (const float*)d_in[9];
    const float* b_nu   = (const float*)d_in[10];
    const float* Wf1    = (const float*)d_in[11];
    const float* bf1    = (const float*)d_in[12];
    const float* Wf2    = (const float*)d_in[13];
    const float* bf2    = (const float*)d_in[14];
    const void* ei = d_in[15];
    const void* bn = d_in[16];
    const void* be = d_in[17];

    float* out = (float*)d_out;

    const size_t SZ_FLAG = 256;
    const size_t SZ_HN   = (size_t)NN * 256;       //  25.6  MB (fp8)
    const size_t SZ_HE   = (size_t)NE * 128;       //  81.92 MB (fp8)
    const size_t SZ_AGG  = (size_t)NN * 256 * 2;   //  51.2  MB (bf16)
    const size_t SZ_R    = (size_t)NN * 512;       //  51.2  MB (fp8)
    const size_t SZ_PERM = (size_t)NE * 4;         //   2.56 MB
    const size_t SZ_INV  = (size_t)NE * 4;
    const size_t SZ_SRC  = (size_t)NE * 4;
    const size_t SZ_DST  = (size_t)NE * 4;
    const size_t SZ_DS   = (size_t)NE * 4;
    const size_t SZ_PTR  = 512 * 1024;
    const size_t SZ_CUR  = 512 * 1024;
    const size_t SZ_W1   = (size_t)3 * 128 * 128;
    const size_t SZ_W2   = (size_t)3 * 256 * 128;
    const size_t SZ_WNU  = (size_t)3 * 256 * 512;
    const size_t SZ_WPRE = (size_t)3 * 512 * 256;
    const size_t NEED = SZ_FLAG + SZ_HN + SZ_HE + SZ_AGG + SZ_R + SZ_PERM +
                        SZ_INV + SZ_SRC + SZ_DST + SZ_DS + SZ_PTR + SZ_CUR +
                        SZ_W1 + SZ_W2 + SZ_WNU + SZ_WPRE;  // ~225 MB

    char* ws = (char*)d_ws;
    int* flag = (int*)ws;                       ws += SZ_FLAG;
    unsigned char* hn8 = (unsigned char*)ws;    ws += SZ_HN;
    unsigned char* he8 = (unsigned char*)ws;    ws += SZ_HE;
    unsigned short* agg = (unsigned short*)ws;  ws += SZ_AGG;
    unsigned char* R = (unsigned char*)ws;      ws += SZ_R;
    int* perm = (int*)ws;                       ws += SZ_PERM;
    int* inv = (int*)ws;                        ws += SZ_INV;
    int* srcs = (int*)ws;                       ws += SZ_SRC;
    int* dsts = (int*)ws;                       ws += SZ_DST;
    float* dist_s = (float*)ws;                 ws += SZ_DS;
    int* rowptr = (int*)ws;                     ws += SZ_PTR;
    int* cursor = (int*)ws;                     ws += SZ_CUR;
    unsigned char* W1T = (unsigned char*)ws;    ws += SZ_W1;
    unsigned char* W2T = (unsigned char*)ws;    ws += SZ_W2;
    unsigned char* WnuT = (unsigned char*)ws;   ws += SZ_WNU;
    unsigned char* WpreT = (unsigned char*)ws;  ws += SZ_WPRE;

    if (ws_size < NEED) {
        float enc = -(100000.0f + (float)(ws_size >> 20));
        k_detect<<<1, 64, 0, stream>>>((const int*)bn, flag);
        k_fill<<<(NB * 256 + 255) / 256, 256, 0, stream>>>(out, NB * 256, enc);
        k_write_batch<<<(NN + 255) / 256, 256, 0, stream>>>(bn, flag, out);
        return;
    }

    k_detect<<<1, 64, 0, stream>>>((const int*)bn, flag);
    k_tr_w1<<<(3 * 128 * 128 + 255) / 256, 256, 0, stream>>>(W_eu, W1T);
    k_tr_w2<<<(3 * 256 * 128 + 255) / 256, 256, 0, stream>>>(W_msg, W2T);
    k_tr_nu<<<(3 * 256 * 512 + 255) / 256, 256, 0, stream>>>(W_nu, WnuT);
    k_tr_pre<<<(3 * 512 * 256 + 255) / 256, 256, 0, stream>>>(W_eu, W_msg, WpreT);
    k_node_embed<<<NN / 8, 256, 0, stream>>>(h_node, W_node, hn8);

    // dst-sorted edge permutation (once; dst constant across layers)
    hipMemsetAsync(cursor, 0, (size_t)NN * 4, stream);
    k_hist<<<(NE + 255) / 256, 256, 0, stream>>>(ei, flag, cursor);
    k_scan<<<1, 1024, 0, stream>>>(cursor, rowptr);
    hipMemcpyAsync(cursor, rowptr, (size_t)NN * 4, hipMemcpyDeviceToDevice, stream);
    k_perm<<<(NE + 255) / 256, 256, 0, stream>>>(ei, flag, pos, cursor, perm,
                                                 inv, srcs, dsts, dist_s);
    k_edge_embed<<<NE / 16, 256, 0, stream>>>(h_edge, W_edge, perm, he8);

    for (int l = 0; l < 3; ++l) {
        hipMemsetAsync(agg, 0, SZ_AGG, stream);
        k_node_pre<<<(NN + 63) / 64, 256, 0, stream>>>(
            hn8, WpreT + (size_t)l * 512 * 256, R);
        k_edge_fused<<<NE / 32, 256, 0, stream>>>(
            he8, R, dist_s, srcs, dsts,
            W1T + (size_t)l * 128 * 128, W_eu + (size_t)l * 641 * 128,
            b_eu + (size_t)l * 128,
            W2T + (size_t)l * 256 * 128, b_msg + (size_t)l * 256, agg);
        k_node_layer<<<(NN + 63) / 64, 256, 0, stream>>>(
            hn8, agg, WnuT + (size_t)l * 256 * 512, b_nu + (size_t)l * 256);
    }

    k_pool_mlp<<<NB, 512, 0, stream>>>(hn8, he8, inv, bn, be, flag,
                                       Wf1, bf1, Wf2, bf2, out);
    k_write_batch<<<(NN + 255) / 256, 256, 0, stream>>>(bn, flag, out);
}

// Round 11
// 1776.195 us; speedup vs baseline: 1.0873x; 1.0873x over previous
//
#include <hip/hip_runtime.h>
#include <hip/hip_bf16.h>
#include <math.h>

#define NN 100000
#define NE 640000
#define NB 2000

typedef __attribute__((ext_vector_type(4))) float v4f;
typedef long long ll64;
#define MFMA8(a, b, c) __builtin_amdgcn_mfma_f32_16x16x32_fp8_fp8(a, b, c, 0, 0, 0)

// scales: activations x16, weights x256, accum de-scale 1/4096
#define INV_S 0.000244140625f
#define ASCL 16.0f
#define AINV 0.0625f

#if __has_builtin(__builtin_amdgcn_cvt_pk_fp8_f32) && __has_builtin(__builtin_amdgcn_cvt_f32_fp8)
#define HW_FP8 1
#else
#define HW_FP8 0
#endif

// ---------- int32/int64 index handling --------------------------------------
__device__ __forceinline__ int IDX(const void* p, size_t i, int is64) {
    return is64 ? (int)((const long long*)p)[i] : ((const int*)p)[i];
}
__device__ __forceinline__ int clampi(int v, int n) {
    return ((unsigned)v < (unsigned)n) ? v : 0;
}

__global__ void k_detect(const int* bn32, int* flag) {
    if (threadIdx.x == 0 && blockIdx.x == 0) {
        int is64 = 1;
        for (int k = 50001; k < 50401; k += 2)
            if (bn32[k] != 0) { is64 = 0; break; }
        *flag = is64;
    }
}

// ---------- fp8 e4m3 codec: HW cvt on gfx950, software fallback -------------
__device__ __forceinline__ unsigned sw_enc_fp8(float x) {
    unsigned s = (__float_as_uint(x) >> 24) & 0x80u;
    float ax = fminf(fabsf(x), 448.f);
    if (ax < 0.015625f) {
        unsigned m = (unsigned)(ax * 512.f + 0.5f);
        return s | m;
    }
    unsigned b = __float_as_uint(ax) + 0x00080000u;
    unsigned e = (b >> 23) - 120u;
    unsigned m = (b >> 20) & 7u;
    unsigned v = (e << 3) | m;
    if (v > 0x7Eu) v = 0x7Eu;
    return s | v;
}
__device__ __forceinline__ float sw_dec_fp8(unsigned b) {
    unsigned s = (b & 0x80u) << 24;
    unsigned e = (b >> 3) & 15u;
    unsigned m = b & 7u;
    if (e) return __uint_as_float(s | ((e + 120u) << 23) | (m << 20));
    float f = (float)m * 0.001953125f;
    return (b & 0x80u) ? -f : f;
}
__device__ __forceinline__ unsigned enc1(float x) {
#if HW_FP8
    return (unsigned)__builtin_amdgcn_cvt_pk_fp8_f32(x, x, 0, false) & 255u;
#else
    return sw_enc_fp8(x);
#endif
}
__device__ __forceinline__ unsigned encpk(float a, float b) {
#if HW_FP8
    return (unsigned)__builtin_amdgcn_cvt_pk_fp8_f32(a, b, 0, false) & 0xFFFFu;
#else
    return sw_enc_fp8(a) | (sw_enc_fp8(b) << 8);
#endif
}
__device__ __forceinline__ float dec1(unsigned b) {
#if HW_FP8
    return __builtin_amdgcn_cvt_f32_fp8((int)b, 0);
#else
    return sw_dec_fp8(b);
#endif
}
__device__ __forceinline__ float bf_f(unsigned short u) {
    return __uint_as_float((unsigned)u << 16);
}
__device__ __forceinline__ unsigned short f_to_bf(float x) {
    __hip_bfloat16 h = __float2bfloat16(x);
    return *(unsigned short*)&h;
}

// ---------- node type embed -------------------------------------------------
__global__ __launch_bounds__(256) void k_node_embed(const float* __restrict__ h_node,
                                                    const float* __restrict__ W,
                                                    unsigned char* __restrict__ hn8) {
    __shared__ float sh[8][16];
    int t = threadIdx.x;
    int r0 = blockIdx.x * 8;
    if (t < 128) sh[t >> 4][t & 15] = h_node[r0 * 16 + t];
    float w[16];
#pragma unroll
    for (int k = 0; k < 16; ++k) w[k] = W[k * 256 + t];
    __syncthreads();
#pragma unroll
    for (int r = 0; r < 8; ++r) {
        float acc = 0.f;
#pragma unroll
        for (int k = 0; k < 16; ++k) acc += sh[r][k] * w[k];
        hn8[(size_t)(r0 + r) * 256 + t] = (unsigned char)enc1(ASCL * acc);
    }
}

// ---------- edge type embed: write he8 in dst-sorted slot order -------------
__global__ __launch_bounds__(256) void k_edge_embed(const float* __restrict__ h_edge,
                                                    const float* __restrict__ W,
                                                    const int* __restrict__ perm,
                                                    unsigned char* __restrict__ he8) {
    __shared__ float sh[16][5];
    int t = threadIdx.x;
    int e0 = blockIdx.x * 16;
    if (t < 80) {
        int row = t / 5, col = t % 5;
        int e = perm[e0 + row];
        sh[row][col] = h_edge[(size_t)e * 5 + col];
    }
    int c = t & 127;
    int es = t >> 7;
    float w[5];
#pragma unroll
    for (int k = 0; k < 5; ++k) w[k] = W[k * 128 + c];
    __syncthreads();
#pragma unroll
    for (int e = 0; e < 8; ++e) {
        int ee = es * 8 + e;
        float acc = 0.f;
#pragma unroll
        for (int k = 0; k < 5; ++k) acc += sh[ee][k] * w[k];
        he8[(size_t)(e0 + ee) * 128 + c] = (unsigned char)enc1(ASCL * acc);
    }
}

// ---------- weight transposes (fp8, x256) -----------------------------------
__global__ __launch_bounds__(256) void k_tr_w1(const float* __restrict__ W,
                                               unsigned char* __restrict__ WT) {
    int i = blockIdx.x * 256 + threadIdx.x;
    if (i >= 3 * 128 * 128) return;
    int l = i / 16384, r = i % 16384;
    int n = r / 128, k = r % 128;
    WT[i] = (unsigned char)enc1(256.f * W[(size_t)l * 641 * 128 + (size_t)k * 128 + n]);
}
__global__ __launch_bounds__(256) void k_tr_w2(const float* __restrict__ W,
                                               unsigned char* __restrict__ WT) {
    int i = blockIdx.x * 256 + threadIdx.x;
    if (i >= 3 * 256 * 128) return;
    int l = i / 32768, r = i % 32768;
    int n = r / 128, k = r % 128;
    WT[i] = (unsigned char)enc1(256.f * W[(size_t)l * 384 * 256 + (size_t)(256 + k) * 256 + n]);
}
__global__ __launch_bounds__(256) void k_tr_nu(const float* __restrict__ W,
                                               unsigned char* __restrict__ WT) {
    int i = blockIdx.x * 256 + threadIdx.x;
    if (i >= 3 * 256 * 512) return;
    int l = i / 131072, r = i % 131072;
    int n = r / 512, k = r % 512;
    WT[i] = (unsigned char)enc1(256.f * W[(size_t)l * 512 * 256 + (size_t)k * 256 + n]);
}
// WpreT[l][n][k] n<512,k<256 : [Psrc | Pdst | Q] weight blocks
__global__ __launch_bounds__(256) void k_tr_pre(const float* __restrict__ Weu,
                                                const float* __restrict__ Wmsg,
                                                unsigned char* __restrict__ WT) {
    int i = blockIdx.x * 256 + threadIdx.x;
    if (i >= 3 * 512 * 256) return;
    int l = i / 131072, r = i % 131072;
    int n = r / 256, k = r % 256;
    float w;
    if (n < 128)      w = Weu[(size_t)l * 641 * 128 + (size_t)(128 + k) * 128 + n];
    else if (n < 256) w = Weu[(size_t)l * 641 * 128 + (size_t)(384 + k) * 128 + (n - 128)];
    else              w = Wmsg[(size_t)l * 384 * 256 + (size_t)k * 256 + (n - 256)];
    WT[i] = (unsigned char)enc1(256.f * w);
}

// ---------- dst-sorted edge permutation (built once) ------------------------
__global__ __launch_bounds__(256) void k_hist(const void* __restrict__ ei,
                                              const int* __restrict__ flag,
                                              int* __restrict__ hist) {
    int e = blockIdx.x * 256 + threadIdx.x;
    if (e >= NE) return;
    int d = clampi(IDX(ei, (size_t)NE + e, *flag), NN);
    atomicAdd(&hist[d], 1);
}
__global__ __launch_bounds__(1024) void k_scan(const int* __restrict__ hist,
                                               int* __restrict__ rowptr) {
    __shared__ int part[1024];
    int t = threadIdx.x;
    const int C = 98;
    int s = 0;
    for (int j = 0; j < C; ++j) {
        int i = t * C + j;
        if (i < NN) s += hist[i];
    }
    part[t] = s;
    __syncthreads();
    if (t == 0) {
        int run = 0;
        for (int i = 0; i < 1024; ++i) { int v = part[i]; part[i] = run; run += v; }
    }
    __syncthreads();
    int run = part[t];
    for (int j = 0; j < C; ++j) {
        int i = t * C + j;
        if (i < NN) { rowptr[i] = run; run += hist[i]; }
    }
}
__global__ __launch_bounds__(256) void k_perm(const void* __restrict__ ei,
                                              const int* __restrict__ flag,
                                              const float* __restrict__ pos,
                                              int* __restrict__ cursor,
                                              int* __restrict__ perm,
                                              int* __restrict__ inv,
                                              int* __restrict__ srcs,
                                              int* __restrict__ dsts,
                                              float* __restrict__ dist_s) {
    int e = blockIdx.x * 256 + threadIdx.x;
    if (e >= NE) return;
    int is64 = *flag;
    int s = clampi(IDX(ei, (size_t)e, is64), NN);
    int d = clampi(IDX(ei, (size_t)NE + e, is64), NN);
    int p = atomicAdd(&cursor[d], 1);
    perm[p] = e;
    inv[e] = p;
    srcs[p] = s;
    dsts[p] = d;
    float dx = pos[d * 3 + 0] - pos[s * 3 + 0];
    float dy = pos[d * 3 + 1] - pos[s * 3 + 1];
    float dz = pos[d * 3 + 2] - pos[s * 3 + 2];
    dist_s[p] = sqrtf(dx * dx + dy * dy + dz * dz);
}

// ---------- node-side precompute (initial layer only): R = hn @ WpreT -------
#define NP_AS 264
__global__ __launch_bounds__(256, 3) void k_node_pre(
    const unsigned char* __restrict__ hn8, const unsigned char* __restrict__ WpreT,
    unsigned char* __restrict__ R) {
    __shared__ unsigned char s_A[64 * NP_AS];
    int t = threadIdx.x;
    int rb = blockIdx.x * 64;
    {
        int row = t >> 2, sb = t & 3;
        int gr = rb + row; if (gr >= NN) gr = NN - 1;
        const uint4* sp = (const uint4*)(hn8 + (size_t)gr * 256 + sb * 64);
        uint4 a = sp[0], b = sp[1], c = sp[2], d = sp[3];
        uint4* dp = (uint4*)&s_A[row * NP_AS + sb * 64];
        dp[0] = a; dp[1] = b; dp[2] = c; dp[3] = d;
    }
    __syncthreads();
    int lane = t & 63, wv = t >> 6, quad = lane >> 4, l16 = lane & 15;
    v4f zero4 = {0.f, 0.f, 0.f, 0.f};
#pragma unroll
    for (int pass = 0; pass < 2; ++pass) {
        int nt0 = wv * 8 + pass * 4;
        v4f acc[4][4];
#pragma unroll
        for (int mt = 0; mt < 4; ++mt)
#pragma unroll
            for (int nl = 0; nl < 4; ++nl) acc[mt][nl] = zero4;
#pragma unroll 2
        for (int k = 0; k < 256; k += 32) {
            int ko = k + quad * 8;
            ll64 b[4];
#pragma unroll
            for (int nl = 0; nl < 4; ++nl)
                b[nl] = *(const ll64*)(WpreT + (size_t)((nt0 + nl) * 16 + l16) * 256 + ko);
#pragma unroll
            for (int mt = 0; mt < 4; ++mt) {
                ll64 a = *(const ll64*)&s_A[(mt * 16 + l16) * NP_AS + ko];
#pragma unroll
                for (int nl = 0; nl < 4; ++nl) acc[mt][nl] = MFMA8(a, b[nl], acc[mt][nl]);
            }
        }
#pragma unroll
        for (int nl = 0; nl < 4; ++nl) {
            int c = (nt0 + nl) * 16 + l16;
#pragma unroll
            for (int mt = 0; mt < 4; ++mt)
#pragma unroll
                for (int rr = 0; rr < 2; ++rr) {
                    int rw0 = mt * 16 + quad * 4 + rr * 2;
                    unsigned pk = encpk(acc[mt][nl][rr * 2] * 0.00390625f,
                                        acc[mt][nl][rr * 2 + 1] * 0.00390625f);
                    if (rb + rw0 < NN)
                        R[(size_t)(rb + rw0) * 512 + c] = (unsigned char)(pk & 255u);
                    if (rb + rw0 + 1 < NN)
                        R[(size_t)(rb + rw0 + 1) * 512 + c] = (unsigned char)(pk >> 8);
                }
        }
    }
}

// ---------- fused edge+msg kernel: 32 sorted edges/block, 4 waves -----------
#define EF_S 136
#define EF_QS 264
#define EF_MS 264
__global__ __launch_bounds__(256, 4) void k_edge_fused(
    unsigned char* __restrict__ he8, const unsigned char* __restrict__ R,
    const float* __restrict__ dist_s,
    const int* __restrict__ srcs, const int* __restrict__ dsts,
    const unsigned char* __restrict__ W1T, const float* __restrict__ W_eu,
    const float* __restrict__ b_eu,
    const unsigned char* __restrict__ W2T, const float* __restrict__ b_msg,
    unsigned short* __restrict__ agg) {
    __shared__ __align__(16) unsigned char s_A[32 * EF_S];
    __shared__ __align__(16) unsigned char s_Pd[32 * EF_S];
    __shared__ __align__(16) unsigned char s_Ph[32 * EF_S];
    __shared__ __align__(16) unsigned char s_Q[32 * EF_QS];
    __shared__ __align__(16) unsigned short s_msg[32 * EF_MS];
    __shared__ float s_dist[32];
    __shared__ int s_dsti[32];
    int t = threadIdx.x;
    int eb = blockIdx.x * 32;
    int row = t >> 3, sb = t & 7;
    int sid = srcs[eb + row];
    int did = dsts[eb + row];
    if (t < 32) {
        s_dsti[t] = dsts[eb + t];
        s_dist[t] = dist_s[eb + t];
    }
    *(uint4*)&s_A[row * EF_S + sb * 16] =
        *(const uint4*)(he8 + (size_t)(eb + row) * 128 + sb * 16);
    *(uint4*)&s_Ph[row * EF_S + sb * 16] =
        *(const uint4*)(R + (size_t)sid * 512 + sb * 16);
    *(uint4*)&s_Pd[row * EF_S + sb * 16] =
        *(const uint4*)(R + (size_t)did * 512 + 128 + sb * 16);
    {
        const uint4* qp = (const uint4*)(R + (size_t)sid * 512 + 256 + sb * 32);
        uint4 q0 = qp[0], q1 = qp[1];
        *(uint4*)&s_Q[row * EF_QS + sb * 32] = q0;
        *(uint4*)&s_Q[row * EF_QS + sb * 32 + 16] = q1;
    }
    int lane = t & 63, wv = t >> 6, quad = lane >> 4, l16 = lane & 15;
    int n0 = wv * 2;
    const unsigned char* B0 = W1T + (size_t)(n0 * 16 + l16) * 128 + quad * 8;
    ll64 Brg[4][2];
#pragma unroll
    for (int kk = 0; kk < 4; ++kk) {
        Brg[kk][0] = *(const ll64*)(B0 + kk * 32);
        Brg[kk][1] = *(const ll64*)(B0 + 2048 + kk * 32);
    }
    __syncthreads();

    v4f zero4 = {0.f, 0.f, 0.f, 0.f};
    v4f acc[2][2];
    acc[0][0] = zero4; acc[0][1] = zero4; acc[1][0] = zero4; acc[1][1] = zero4;
#pragma unroll
    for (int kk = 0; kk < 4; ++kk) {
        int ko = kk * 32 + quad * 8;
#pragma unroll
        for (int mt = 0; mt < 2; ++mt) {
            ll64 a = *(const ll64*)&s_A[(mt * 16 + l16) * EF_S + ko];
            acc[mt][0] = MFMA8(a, Brg[kk][0], acc[mt][0]);
            acc[mt][1] = MFMA8(a, Brg[kk][1], acc[mt][1]);
        }
    }
#pragma unroll
    for (int nl = 0; nl < 2; ++nl) {
        int c = (n0 + nl) * 16 + l16;
        float w640 = W_eu[640 * 128 + c];
        float bb = b_eu[c];
#pragma unroll
        for (int mt = 0; mt < 2; ++mt)
#pragma unroll
            for (int rr = 0; rr < 2; ++rr) {
                int rw0 = mt * 16 + quad * 4 + rr * 2;
                int rw1 = rw0 + 1;
                float S0 = (dec1(s_Ph[rw0 * EF_S + c]) +
                            dec1(s_Pd[rw0 * EF_S + c])) * AINV;
                float S1 = (dec1(s_Ph[rw1 * EF_S + c]) +
                            dec1(s_Pd[rw1 * EF_S + c])) * AINV;
                float v0 = fmaxf(acc[mt][nl][rr * 2] * INV_S + S0 +
                                 s_dist[rw0] * w640 + bb, 0.f);
                float v1 = fmaxf(acc[mt][nl][rr * 2 + 1] * INV_S + S1 +
                                 s_dist[rw1] * w640 + bb, 0.f);
                unsigned pk = encpk(ASCL * v0, ASCL * v1);
                unsigned char q0 = (unsigned char)(pk & 255u);
                unsigned char q1 = (unsigned char)(pk >> 8);
                s_Ph[rw0 * EF_S + c] = q0;
                s_Ph[rw1 * EF_S + c] = q1;
                he8[(size_t)(eb + rw0) * 128 + c] = q0;
                he8[(size_t)(eb + rw1) * 128 + c] = q1;
            }
    }
    __syncthreads();

    v4f mac[2][4];
#pragma unroll
    for (int nl = 0; nl < 4; ++nl) { mac[0][nl] = zero4; mac[1][nl] = zero4; }
    int q0n = wv * 4;
#pragma unroll
    for (int kk = 0; kk < 4; ++kk) {
        int ko = kk * 32 + quad * 8;
        ll64 b[4];
#pragma unroll
        for (int nl = 0; nl < 4; ++nl)
            b[nl] = *(const ll64*)(W2T + (size_t)((q0n + nl) * 16 + l16) * 128 + ko);
#pragma unroll
        for (int mt = 0; mt < 2; ++mt) {
            ll64 a = *(const ll64*)&s_Ph[(mt * 16 + l16) * EF_S + ko];
#pragma unroll
            for (int nl = 0; nl < 4; ++nl) mac[mt][nl] = MFMA8(a, b[nl], mac[mt][nl]);
        }
    }
#pragma unroll
    for (int nl = 0; nl < 4; ++nl) {
        int c = (q0n + nl) * 16 + l16;
        float bm = b_msg[c];
#pragma unroll
        for (int mt = 0; mt < 2; ++mt)
#pragma unroll
            for (int r = 0; r < 4; ++r) {
                int rw = mt * 16 + quad * 4 + r;
                float qv = dec1(s_Q[rw * EF_QS + c]) * AINV;
                float v = fmaxf(mac[mt][nl][r] * INV_S + qv + bm, 0.f);
                s_msg[rw * EF_MS + c] = f_to_bf(v);
            }
    }
    __syncthreads();
    // run-merged packed bf16 atomics (dst sorted within block)
    {
        int cp = t & 127;
        int half = t >> 7;
        int r0 = half * 16, r1 = r0 + 16;
        float ax = 0.f, ay = 0.f;
        int cur = s_dsti[r0];
        for (int rw = r0; rw < r1; ++rw) {
            int d2 = s_dsti[rw];
            if (d2 != cur) {
                if (ax != 0.f || ay != 0.f) {
                    __hip_bfloat162 pv;
                    pv.x = __float2bfloat16(ax);
                    pv.y = __float2bfloat16(ay);
                    unsafeAtomicAdd((__hip_bfloat162*)&agg[(size_t)cur * 256 + cp * 2], pv);
                }
                ax = 0.f; ay = 0.f; cur = d2;
            }
            unsigned v = *(const unsigned*)&s_msg[rw * EF_MS + cp * 2];
            ax += bf_f((unsigned short)(v & 0xFFFFu));
            ay += bf_f((unsigned short)(v >> 16));
        }
        if (ax != 0.f || ay != 0.f) {
            __hip_bfloat162 pv;
            pv.x = __float2bfloat16(ax);
            pv.y = __float2bfloat16(ay);
            unsafeAtomicAdd((__hip_bfloat162*)&agg[(size_t)cur * 256 + cp * 2], pv);
        }
    }
}

// ---------- fused node update + next-layer precompute -----------------------
// GEMM1: hn_new = hn + relu([hn|agg]@W_nu + b)   (K=512)
// GEMM2 (if do_pre): R = hn_new @ WpreT_next      (K=256, N=512)
#define NF_AS 520
#define NF_BS 264
__global__ __launch_bounds__(256, 3) void k_node_fused(
    unsigned char* __restrict__ hn8, const unsigned short* __restrict__ agg,
    const unsigned char* __restrict__ WnuT, const float* __restrict__ b,
    const unsigned char* __restrict__ WpreT, unsigned char* __restrict__ R,
    int do_pre) {
    __shared__ unsigned char s_A[64 * NF_AS];  // 33.3 KB
    __shared__ unsigned char s_B[64 * NF_BS];  // 16.9 KB: hn_new for GEMM2
    int t = threadIdx.x;
    int rb = blockIdx.x * 64;
    {
        int row = t >> 2, sb = t & 3;
        int gr = rb + row; if (gr >= NN) gr = NN - 1;
        const uint4* sp = (const uint4*)(hn8 + (size_t)gr * 256 + sb * 64);
        uint4 a = sp[0], b2 = sp[1], c = sp[2], d = sp[3];
        uint4* dp = (uint4*)&s_A[row * NF_AS + sb * 64];
        dp[0] = a; dp[1] = b2; dp[2] = c; dp[3] = d;
        const unsigned short* ap = agg + (size_t)gr * 256 + sb * 64;
        unsigned char* dq = &s_A[row * NF_AS + 256 + sb * 64];
#pragma unroll
        for (int j = 0; j < 64; j += 2) {
            unsigned pk = encpk(ASCL * bf_f(ap[j]), ASCL * bf_f(ap[j + 1]));
            *(unsigned short*)&dq[j] = (unsigned short)pk;
        }
    }
    __syncthreads();
    int lane = t & 63, wv = t >> 6, quad = lane >> 4, l16 = lane & 15;
    v4f zero4 = {0.f, 0.f, 0.f, 0.f};
    {
        v4f acc[4][4];
#pragma unroll
        for (int mt = 0; mt < 4; ++mt)
#pragma unroll
            for (int nl = 0; nl < 4; ++nl) acc[mt][nl] = zero4;
        int q0 = wv * 4;
#pragma unroll 2
        for (int k = 0; k < 512; k += 32) {
            int ko = k + quad * 8;
            ll64 b2[4];
#pragma unroll
            for (int nl = 0; nl < 4; ++nl)
                b2[nl] = *(const ll64*)(WnuT + (size_t)((q0 + nl) * 16 + l16) * 512 + ko);
#pragma unroll
            for (int mt = 0; mt < 4; ++mt) {
                ll64 a = *(const ll64*)&s_A[(mt * 16 + l16) * NF_AS + ko];
#pragma unroll
                for (int nl = 0; nl < 4; ++nl) acc[mt][nl] = MFMA8(a, b2[nl], acc[mt][nl]);
            }
        }
#pragma unroll
        for (int nl = 0; nl < 4; ++nl) {
            int c = (q0 + nl) * 16 + l16;
            float bv = b[c];
#pragma unroll
            for (int mt = 0; mt < 4; ++mt)
#pragma unroll
                for (int rr = 0; rr < 2; ++rr) {
                    int rw0 = mt * 16 + quad * 4 + rr * 2;
                    float o0 = dec1(s_A[rw0 * NF_AS + c]) * AINV;
                    float o1 = dec1(s_A[(rw0 + 1) * NF_AS + c]) * AINV;
                    float v0 = o0 + fmaxf(acc[mt][nl][rr * 2] * INV_S + bv, 0.f);
                    float v1 = o1 + fmaxf(acc[mt][nl][rr * 2 + 1] * INV_S + bv, 0.f);
                    unsigned pk = encpk(ASCL * v0, ASCL * v1);
                    unsigned char q0b = (unsigned char)(pk & 255u);
                    unsigned char q1b = (unsigned char)(pk >> 8);
                    s_B[rw0 * NF_BS + c] = q0b;
                    s_B[(rw0 + 1) * NF_BS + c] = q1b;
                    if (rb + rw0 < NN)
                        hn8[(size_t)(rb + rw0) * 256 + c] = q0b;
                    if (rb + rw0 + 1 < NN)
                        hn8[(size_t)(rb + rw0 + 1) * 256 + c] = q1b;
                }
        }
    }
    if (!do_pre) return;
    __syncthreads();
    // GEMM2: R = hn_new @ WpreT (K=256, N=512)
#pragma unroll
    for (int pass = 0; pass < 2; ++pass) {
        int nt0 = wv * 8 + pass * 4;
        v4f acc[4][4];
#pragma unroll
        for (int mt = 0; mt < 4; ++mt)
#pragma unroll
            for (int nl = 0; nl < 4; ++nl) acc[mt][nl] = zero4;
#pragma unroll 2
        for (int k = 0; k < 256; k += 32) {
            int ko = k + quad * 8;
            ll64 b2[4];
#pragma unroll
            for (int nl = 0; nl < 4; ++nl)
                b2[nl] = *(const ll64*)(WpreT + (size_t)((nt0 + nl) * 16 + l16) * 256 + ko);
#pragma unroll
            for (int mt = 0; mt < 4; ++mt) {
                ll64 a = *(const ll64*)&s_B[(mt * 16 + l16) * NF_BS + ko];
#pragma unroll
                for (int nl = 0; nl < 4; ++nl) acc[mt][nl] = MFMA8(a, b2[nl], acc[mt][nl]);
            }
        }
#pragma unroll
        for (int nl = 0; nl < 4; ++nl) {
            int c = (nt0 + nl) * 16 + l16;
#pragma unroll
            for (int mt = 0; mt < 4; ++mt)
#pragma unroll
                for (int rr = 0; rr < 2; ++rr) {
                    int rw0 = mt * 16 + quad * 4 + rr * 2;
                    unsigned pk = encpk(acc[mt][nl][rr * 2] * 0.00390625f,
                                        acc[mt][nl][rr * 2 + 1] * 0.00390625f);
                    if (rb + rw0 < NN)
                        R[(size_t)(rb + rw0) * 512 + c] = (unsigned char)(pk & 255u);
                    if (rb + rw0 + 1 < NN)
                        R[(size_t)(rb + rw0 + 1) * 512 + c] = (unsigned char)(pk >> 8);
                }
        }
    }
}

// ---------- pooling + final MLP (wave-cooperative row reads) ----------------
__device__ __forceinline__ int lbound(const void* a, int n, int v, int is64) {
    int lo = 0, hi = n;
    while (lo < hi) {
        int mid = (lo + hi) >> 1;
        if (IDX(a, mid, is64) < v) lo = mid + 1; else hi = mid;
    }
    return lo;
}

__global__ __launch_bounds__(512) void k_pool_mlp(
    const unsigned char* __restrict__ hn8, const unsigned char* __restrict__ he8,
    const int* __restrict__ inv,
    const void* __restrict__ bn, const void* __restrict__ be,
    const int* __restrict__ flag,
    const float* __restrict__ Wf1, const float* __restrict__ bf1,
    const float* __restrict__ Wf2, const float* __restrict__ bf2,
    float* __restrict__ out) {
    __shared__ float s_nacc[8][256];
    __shared__ float s_eacc[16][128];
    __shared__ float s_sub[384];
    __shared__ float s_hid[512];
    int b = blockIdx.x;
    int t = threadIdx.x;
    int is64 = *flag;
    int lane = t & 63, wv = t >> 6;  // 8 waves
    int nlo = lbound(bn, NN, b, is64), nhi = lbound(bn, NN, b + 1, is64);
    int elo = lbound(be, NE, b, is64), ehi = lbound(be, NE, b + 1, is64);
    // node mean: wave per row (256B = 64 lanes x 4B), 8 rows in flight
    {
        float a0 = 0.f, a1 = 0.f, a2 = 0.f, a3 = 0.f;
        for (int i = nlo + wv; i < nhi; i += 8) {
            unsigned u = *(const unsigned*)(hn8 + (size_t)i * 256 + lane * 4);
            a0 += dec1(u & 255u);
            a1 += dec1((u >> 8) & 255u);
            a2 += dec1((u >> 16) & 255u);
            a3 += dec1(u >> 24);
        }
        s_nacc[wv][lane * 4 + 0] = a0;
        s_nacc[wv][lane * 4 + 1] = a1;
        s_nacc[wv][lane * 4 + 2] = a2;
        s_nacc[wv][lane * 4 + 3] = a3;
    }
    // edge mean: half-wave per row (128B = 32 lanes x 4B), 16 rows in flight
    {
        int g16 = wv * 2 + (lane >> 5);
        int sl = lane & 31;
        float a0 = 0.f, a1 = 0.f, a2 = 0.f, a3 = 0.f;
        for (int e = elo + g16; e < ehi; e += 16) {
            int row = inv[e];
            unsigned u = *(const unsigned*)(he8 + (size_t)row * 128 + sl * 4);
            a0 += dec1(u & 255u);
            a1 += dec1((u >> 8) & 255u);
            a2 += dec1((u >> 16) & 255u);
            a3 += dec1(u >> 24);
        }
        s_eacc[g16][sl * 4 + 0] = a0;
        s_eacc[g16][sl * 4 + 1] = a1;
        s_eacc[g16][sl * 4 + 2] = a2;
        s_eacc[g16][sl * 4 + 3] = a3;
    }
    __syncthreads();
    if (t < 256) {
        float s = 0.f;
#pragma unroll
        for (int w = 0; w < 8; ++w) s += s_nacc[w][t];
        s_sub[t] = s * AINV / fmaxf((float)(nhi - nlo), 1.f);
    } else if (t < 384) {
        int c = t - 256;
        float s = 0.f;
#pragma unroll
        for (int j = 0; j < 16; ++j) s += s_eacc[j][c];
        s_sub[t] = s * AINV / fmaxf((float)(ehi - elo), 1.f);
    }
    __syncthreads();
    float hacc = bf1[t];
    for (int k = 0; k < 384; ++k) hacc += s_sub[k] * Wf1[k * 512 + t];
    s_hid[t] = fmaxf(hacc, 0.f);
    __syncthreads();
    if (t < 256) {
        float o = bf2[t];
        for (int k = 0; k < 512; ++k) o += s_hid[k] * Wf2[k * 256 + t];
        out[(size_t)b * 256 + t] = o;
    }
}

// ---------- second output ---------------------------------------------------
__global__ __launch_bounds__(256) void k_write_batch(const void* __restrict__ bn,
                                                     const int* __restrict__ flag,
                                                     float* __restrict__ out) {
    int i = blockIdx.x * 256 + threadIdx.x;
    if (i < NN) out[(size_t)NB * 256 + i] = (float)IDX(bn, i, *flag);
}

__global__ __launch_bounds__(256) void k_fill(float* __restrict__ p, int n, float v) {
    int i = blockIdx.x * 256 + threadIdx.x;
    if (i < n) p[i] = v;
}

extern "C" void kernel_launch(void* const* d_in, const int* in_sizes, int n_in,
                              void* d_out, int out_size, void* d_ws, size_t ws_size,
                              hipStream_t stream) {
    const float* h_node = (const float*)d_in[0];
    const float* pos    = (const float*)d_in[1];
    const float* h_edge = (const float*)d_in[2];
    const float* W_node = (const float*)d_in[3];
    const float* W_edge = (const float*)d_in[4];
    const float* W_eu   = (const float*)d_in[5];
    const float* b_eu   = (const float*)d_in[6];
    const float* W_msg  = (const float*)d_in[7];
    const float* b_msg  = (const float*)d_in[8];
    const float* W_nu   = (const float*)d_in[9];
    const float* b_nu   = (const float*)d_in[10];
    const float* Wf1    = (const float*)d_in[11];
    const float* bf1    = (const float*)d_in[12];
    const float* Wf2    = (const float*)d_in[13];
    const float* bf2    = (const float*)d_in[14];
    const void* ei = d_in[15];
    const void* bn = d_in[16];
    const void* be = d_in[17];

    float* out = (float*)d_out;

    const size_t SZ_FLAG = 256;
    const size_t SZ_HN   = (size_t)NN * 256;
    const size_t SZ_HE   = (size_t)NE * 128;
    const size_t SZ_AGG  = (size_t)NN * 256 * 2;
    const size_t SZ_R    = (size_t)NN * 512;
    const size_t SZ_PERM = (size_t)NE * 4;
    const size_t SZ_INV  = (size_t)NE * 4;
    const size_t SZ_SRC  = (size_t)NE * 4;
    const size_t SZ_DST  = (size_t)NE * 4;
    const size_t SZ_DS   = (size_t)NE * 4;
    const size_t SZ_PTR  = 512 * 1024;
    const size_t SZ_CUR  = 512 * 1024;
    const size_t SZ_W1   = (size_t)3 * 128 * 128;
    const size_t SZ_W2   = (size_t)3 * 256 * 128;
    const size_t SZ_WNU  = (size_t)3 * 256 * 512;
    const size_t SZ_WPRE = (size_t)3 * 512 * 256;
    const size_t NEED = SZ_FLAG + SZ_HN + SZ_HE + SZ_AGG + SZ_R + SZ_PERM +
                        SZ_INV + SZ_SRC + SZ_DST + SZ_DS + SZ_PTR + SZ_CUR +
                        SZ_W1 + SZ_W2 + SZ_WNU + SZ_WPRE;  // ~225 MB

    char* ws = (char*)d_ws;
    int* flag = (int*)ws;                       ws += SZ_FLAG;
    unsigned char* hn8 = (unsigned char*)ws;    ws += SZ_HN;
    unsigned char* he8 = (unsigned char*)ws;    ws += SZ_HE;
    unsigned short* agg = (unsigned short*)ws;  ws += SZ_AGG;
    unsigned char* R = (unsigned char*)ws;      ws += SZ_R;
    int* perm = (int*)ws;                       ws += SZ_PERM;
    int* inv = (int*)ws;                        ws += SZ_INV;
    int* srcs = (int*)ws;                       ws += SZ_SRC;
    int* dsts = (int*)ws;                       ws += SZ_DST;
    float* dist_s = (float*)ws;                 ws += SZ_DS;
    int* rowptr = (int*)ws;                     ws += SZ_PTR;
    int* cursor = (int*)ws;                     ws += SZ_CUR;
    unsigned char* W1T = (unsigned char*)ws;    ws += SZ_W1;
    unsigned char* W2T = (unsigned char*)ws;    ws += SZ_W2;
    unsigned char* WnuT = (unsigned char*)ws;   ws += SZ_WNU;
    unsigned char* WpreT = (unsigned char*)ws;  ws += SZ_WPRE;

    if (ws_size < NEED) {
        float enc = -(100000.0f + (float)(ws_size >> 20));
        k_detect<<<1, 64, 0, stream>>>((const int*)bn, flag);
        k_fill<<<(NB * 256 + 255) / 256, 256, 0, stream>>>(out, NB * 256, enc);
        k_write_batch<<<(NN + 255) / 256, 256, 0, stream>>>(bn, flag, out);
        return;
    }

    k_detect<<<1, 64, 0, stream>>>((const int*)bn, flag);
    k_tr_w1<<<(3 * 128 * 128 + 255) / 256, 256, 0, stream>>>(W_eu, W1T);
    k_tr_w2<<<(3 * 256 * 128 + 255) / 256, 256, 0, stream>>>(W_msg, W2T);
    k_tr_nu<<<(3 * 256 * 512 + 255) / 256, 256, 0, stream>>>(W_nu, WnuT);
    k_tr_pre<<<(3 * 512 * 256 + 255) / 256, 256, 0, stream>>>(W_eu, W_msg, WpreT);
    k_node_embed<<<NN / 8, 256, 0, stream>>>(h_node, W_node, hn8);

    hipMemsetAsync(cursor, 0, (size_t)NN * 4, stream);
    k_hist<<<(NE + 255) / 256, 256, 0, stream>>>(ei, flag, cursor);
    k_scan<<<1, 1024, 0, stream>>>(cursor, rowptr);
    hipMemcpyAsync(cursor, rowptr, (size_t)NN * 4, hipMemcpyDeviceToDevice, stream);
    k_perm<<<(NE + 255) / 256, 256, 0, stream>>>(ei, flag, pos, cursor, perm,
                                                 inv, srcs, dsts, dist_s);
    k_edge_embed<<<NE / 16, 256, 0, stream>>>(h_edge, W_edge, perm, he8);

    // initial R from embedded hn (layer 0 weights)
    k_node_pre<<<(NN + 63) / 64, 256, 0, stream>>>(hn8, WpreT, R);

    for (int l = 0; l < 3; ++l) {
        hipMemsetAsync(agg, 0, SZ_AGG, stream);
        k_edge_fused<<<NE / 32, 256, 0, stream>>>(
            he8, R, dist_s, srcs, dsts,
            W1T + (size_t)l * 128 * 128, W_eu + (size_t)l * 641 * 128,
            b_eu + (size_t)l * 128,
            W2T + (size_t)l * 256 * 128, b_msg + (size_t)l * 256, agg);
        int do_pre = (l < 2) ? 1 : 0;
        const unsigned char* wpre_next = WpreT + (size_t)(do_pre ? (l + 1) : 0) * 512 * 256;
        k_node_fused<<<(NN + 63) / 64, 256, 0, stream>>>(
            hn8, agg, WnuT + (size_t)l * 256 * 512, b_nu + (size_t)l * 256,
            wpre_next, R, do_pre);
    }

    k_pool_mlp<<<NB, 512, 0, stream>>>(hn8, he8, inv, bn, be, flag,
                                       Wf1, bf1, Wf2, bf2, out);
    k_write_batch<<<(NN + 255) / 256, 256, 0, stream>>>(bn, flag, out);
}

// Round 12
// 1734.369 us; speedup vs baseline: 1.1135x; 1.0241x over previous
//
#include <hip/hip_runtime.h>
#include <hip/hip_bf16.h>
#include <math.h>

#define NN 100000
#define NE 640000
#define NB 2000

typedef __attribute__((ext_vector_type(4))) float v4f;
typedef long long ll64;
#define MFMA8(a, b, c) __builtin_amdgcn_mfma_f32_16x16x32_fp8_fp8(a, b, c, 0, 0, 0)

// scales: activations x16, weights x256, accum de-scale 1/4096
#define INV_S 0.000244140625f
#define ASCL 16.0f
#define AINV 0.0625f

#if __has_builtin(__builtin_amdgcn_cvt_pk_fp8_f32) && __has_builtin(__builtin_amdgcn_cvt_f32_fp8)
#define HW_FP8 1
#else
#define HW_FP8 0
#endif

// ---------- int32/int64 index handling --------------------------------------
__device__ __forceinline__ int IDX(const void* p, size_t i, int is64) {
    return is64 ? (int)((const long long*)p)[i] : ((const int*)p)[i];
}
__device__ __forceinline__ int clampi(int v, int n) {
    return ((unsigned)v < (unsigned)n) ? v : 0;
}

__global__ void k_detect(const int* bn32, int* flag) {
    if (threadIdx.x == 0 && blockIdx.x == 0) {
        int is64 = 1;
        for (int k = 50001; k < 50401; k += 2)
            if (bn32[k] != 0) { is64 = 0; break; }
        *flag = is64;
    }
}

// ---------- fp8 e4m3 codec: HW cvt on gfx950, software fallback -------------
__device__ __forceinline__ unsigned sw_enc_fp8(float x) {
    unsigned s = (__float_as_uint(x) >> 24) & 0x80u;
    float ax = fminf(fabsf(x), 448.f);
    if (ax < 0.015625f) {
        unsigned m = (unsigned)(ax * 512.f + 0.5f);
        return s | m;
    }
    unsigned b = __float_as_uint(ax) + 0x00080000u;
    unsigned e = (b >> 23) - 120u;
    unsigned m = (b >> 20) & 7u;
    unsigned v = (e << 3) | m;
    if (v > 0x7Eu) v = 0x7Eu;
    return s | v;
}
__device__ __forceinline__ float sw_dec_fp8(unsigned b) {
    unsigned s = (b & 0x80u) << 24;
    unsigned e = (b >> 3) & 15u;
    unsigned m = b & 7u;
    if (e) return __uint_as_float(s | ((e + 120u) << 23) | (m << 20));
    float f = (float)m * 0.001953125f;
    return (b & 0x80u) ? -f : f;
}
__device__ __forceinline__ unsigned enc1(float x) {
#if HW_FP8
    return (unsigned)__builtin_amdgcn_cvt_pk_fp8_f32(x, x, 0, false) & 255u;
#else
    return sw_enc_fp8(x);
#endif
}
__device__ __forceinline__ unsigned encpk(float a, float b) {
#if HW_FP8
    return (unsigned)__builtin_amdgcn_cvt_pk_fp8_f32(a, b, 0, false) & 0xFFFFu;
#else
    return sw_enc_fp8(a) | (sw_enc_fp8(b) << 8);
#endif
}
__device__ __forceinline__ float dec1(unsigned b) {
#if HW_FP8
    return __builtin_amdgcn_cvt_f32_fp8((int)b, 0);
#else
    return sw_dec_fp8(b);
#endif
}
__device__ __forceinline__ float bf_f(unsigned short u) {
    return __uint_as_float((unsigned)u << 16);
}

// ---------- node type embed -------------------------------------------------
__global__ __launch_bounds__(256) void k_node_embed(const float* __restrict__ h_node,
                                                    const float* __restrict__ W,
                                                    unsigned char* __restrict__ hn8) {
    __shared__ float sh[8][16];
    int t = threadIdx.x;
    int r0 = blockIdx.x * 8;
    if (t < 128) sh[t >> 4][t & 15] = h_node[r0 * 16 + t];
    float w[16];
#pragma unroll
    for (int k = 0; k < 16; ++k) w[k] = W[k * 256 + t];
    __syncthreads();
#pragma unroll
    for (int r = 0; r < 8; ++r) {
        float acc = 0.f;
#pragma unroll
        for (int k = 0; k < 16; ++k) acc += sh[r][k] * w[k];
        hn8[(size_t)(r0 + r) * 256 + t] = (unsigned char)enc1(ASCL * acc);
    }
}

// ---------- edge type embed: write he8 in dst-sorted slot order -------------
__global__ __launch_bounds__(256) void k_edge_embed(const float* __restrict__ h_edge,
                                                    const float* __restrict__ W,
                                                    const int* __restrict__ perm,
                                                    unsigned char* __restrict__ he8) {
    __shared__ float sh[16][5];
    int t = threadIdx.x;
    int e0 = blockIdx.x * 16;
    if (t < 80) {
        int row = t / 5, col = t % 5;
        int e = perm[e0 + row];
        sh[row][col] = h_edge[(size_t)e * 5 + col];
    }
    int c = t & 127;
    int es = t >> 7;
    float w[5];
#pragma unroll
    for (int k = 0; k < 5; ++k) w[k] = W[k * 128 + c];
    __syncthreads();
#pragma unroll
    for (int e = 0; e < 8; ++e) {
        int ee = es * 8 + e;
        float acc = 0.f;
#pragma unroll
        for (int k = 0; k < 5; ++k) acc += sh[ee][k] * w[k];
        he8[(size_t)(e0 + ee) * 128 + c] = (unsigned char)enc1(ASCL * acc);
    }
}

// ---------- weight transposes (fp8, x256) -----------------------------------
__global__ __launch_bounds__(256) void k_tr_w1(const float* __restrict__ W,
                                               unsigned char* __restrict__ WT) {
    int i = blockIdx.x * 256 + threadIdx.x;
    if (i >= 3 * 128 * 128) return;
    int l = i / 16384, r = i % 16384;
    int n = r / 128, k = r % 128;
    WT[i] = (unsigned char)enc1(256.f * W[(size_t)l * 641 * 128 + (size_t)k * 128 + n]);
}
__global__ __launch_bounds__(256) void k_tr_w2(const float* __restrict__ W,
                                               unsigned char* __restrict__ WT) {
    int i = blockIdx.x * 256 + threadIdx.x;
    if (i >= 3 * 256 * 128) return;
    int l = i / 32768, r = i % 32768;
    int n = r / 128, k = r % 128;
    WT[i] = (unsigned char)enc1(256.f * W[(size_t)l * 384 * 256 + (size_t)(256 + k) * 256 + n]);
}
__global__ __launch_bounds__(256) void k_tr_nu(const float* __restrict__ W,
                                               unsigned char* __restrict__ WT) {
    int i = blockIdx.x * 256 + threadIdx.x;
    if (i >= 3 * 256 * 512) return;
    int l = i / 131072, r = i % 131072;
    int n = r / 512, k = r % 512;
    WT[i] = (unsigned char)enc1(256.f * W[(size_t)l * 512 * 256 + (size_t)k * 256 + n]);
}
// WpreT[l][n][k] n<512,k<256 : [Psrc | Pdst | Q] weight blocks
__global__ __launch_bounds__(256) void k_tr_pre(const float* __restrict__ Weu,
                                                const float* __restrict__ Wmsg,
                                                unsigned char* __restrict__ WT) {
    int i = blockIdx.x * 256 + threadIdx.x;
    if (i >= 3 * 512 * 256) return;
    int l = i / 131072, r = i % 131072;
    int n = r / 256, k = r % 256;
    float w;
    if (n < 128)      w = Weu[(size_t)l * 641 * 128 + (size_t)(128 + k) * 128 + n];
    else if (n < 256) w = Weu[(size_t)l * 641 * 128 + (size_t)(384 + k) * 128 + (n - 128)];
    else              w = Wmsg[(size_t)l * 384 * 256 + (size_t)k * 256 + (n - 256)];
    WT[i] = (unsigned char)enc1(256.f * w);
}

// ---------- dst-sorted edge permutation (built once) ------------------------
__global__ __launch_bounds__(256) void k_hist(const void* __restrict__ ei,
                                              const int* __restrict__ flag,
                                              int* __restrict__ hist) {
    int e = blockIdx.x * 256 + threadIdx.x;
    if (e >= NE) return;
    int d = clampi(IDX(ei, (size_t)NE + e, *flag), NN);
    atomicAdd(&hist[d], 1);
}
__global__ __launch_bounds__(1024) void k_scan(const int* __restrict__ hist,
                                               int* __restrict__ rowptr) {
    __shared__ int part[1024];
    int t = threadIdx.x;
    const int C = 98;
    int s = 0;
    for (int j = 0; j < C; ++j) {
        int i = t * C + j;
        if (i < NN) s += hist[i];
    }
    part[t] = s;
    __syncthreads();
    if (t == 0) {
        int run = 0;
        for (int i = 0; i < 1024; ++i) { int v = part[i]; part[i] = run; run += v; }
    }
    __syncthreads();
    int run = part[t];
    for (int j = 0; j < C; ++j) {
        int i = t * C + j;
        if (i < NN) { rowptr[i] = run; run += hist[i]; }
    }
}
__global__ __launch_bounds__(256) void k_perm(const void* __restrict__ ei,
                                              const int* __restrict__ flag,
                                              const float* __restrict__ pos,
                                              int* __restrict__ cursor,
                                              int* __restrict__ perm,
                                              int* __restrict__ inv,
                                              int* __restrict__ srcs,
                                              int* __restrict__ dsts,
                                              float* __restrict__ dist_s) {
    int e = blockIdx.x * 256 + threadIdx.x;
    if (e >= NE) return;
    int is64 = *flag;
    int s = clampi(IDX(ei, (size_t)e, is64), NN);
    int d = clampi(IDX(ei, (size_t)NE + e, is64), NN);
    int p = atomicAdd(&cursor[d], 1);
    perm[p] = e;
    inv[e] = p;
    srcs[p] = s;
    dsts[p] = d;
    float dx = pos[d * 3 + 0] - pos[s * 3 + 0];
    float dy = pos[d * 3 + 1] - pos[s * 3 + 1];
    float dz = pos[d * 3 + 2] - pos[s * 3 + 2];
    dist_s[p] = sqrtf(dx * dx + dy * dy + dz * dz);
}

// ---------- node-side precompute (initial layer only): R = hn @ WpreT -------
#define NP_AS 264
__global__ __launch_bounds__(256, 3) void k_node_pre(
    const unsigned char* __restrict__ hn8, const unsigned char* __restrict__ WpreT,
    unsigned char* __restrict__ R) {
    __shared__ unsigned char s_A[64 * NP_AS];
    int t = threadIdx.x;
    int rb = blockIdx.x * 64;
    {
        int row = t >> 2, sb = t & 3;
        int gr = rb + row; if (gr >= NN) gr = NN - 1;
        const uint4* sp = (const uint4*)(hn8 + (size_t)gr * 256 + sb * 64);
        uint4 a = sp[0], b = sp[1], c = sp[2], d = sp[3];
        uint4* dp = (uint4*)&s_A[row * NP_AS + sb * 64];
        dp[0] = a; dp[1] = b; dp[2] = c; dp[3] = d;
    }
    __syncthreads();
    int lane = t & 63, wv = t >> 6, quad = lane >> 4, l16 = lane & 15;
    v4f zero4 = {0.f, 0.f, 0.f, 0.f};
#pragma unroll
    for (int pass = 0; pass < 2; ++pass) {
        int nt0 = wv * 8 + pass * 4;
        v4f acc[4][4];
#pragma unroll
        for (int mt = 0; mt < 4; ++mt)
#pragma unroll
            for (int nl = 0; nl < 4; ++nl) acc[mt][nl] = zero4;
#pragma unroll 2
        for (int k = 0; k < 256; k += 32) {
            int ko = k + quad * 8;
            ll64 b[4];
#pragma unroll
            for (int nl = 0; nl < 4; ++nl)
                b[nl] = *(const ll64*)(WpreT + (size_t)((nt0 + nl) * 16 + l16) * 256 + ko);
#pragma unroll
            for (int mt = 0; mt < 4; ++mt) {
                ll64 a = *(const ll64*)&s_A[(mt * 16 + l16) * NP_AS + ko];
#pragma unroll
                for (int nl = 0; nl < 4; ++nl) acc[mt][nl] = MFMA8(a, b[nl], acc[mt][nl]);
            }
        }
#pragma unroll
        for (int nl = 0; nl < 4; ++nl) {
            int c = (nt0 + nl) * 16 + l16;
#pragma unroll
            for (int mt = 0; mt < 4; ++mt)
#pragma unroll
                for (int rr = 0; rr < 2; ++rr) {
                    int rw0 = mt * 16 + quad * 4 + rr * 2;
                    unsigned pk = encpk(acc[mt][nl][rr * 2] * 0.00390625f,
                                        acc[mt][nl][rr * 2 + 1] * 0.00390625f);
                    if (rb + rw0 < NN)
                        R[(size_t)(rb + rw0) * 512 + c] = (unsigned char)(pk & 255u);
                    if (rb + rw0 + 1 < NN)
                        R[(size_t)(rb + rw0 + 1) * 512 + c] = (unsigned char)(pk >> 8);
                }
        }
    }
}

// ---------- fused edge+msg kernel: 32 sorted edges/block, 4 waves -----------
// LDS ~26.3 KB -> 6 blocks/CU. Epilogues write LDS only; cooperative uint4
// write-back for he8; fp8 s_msg; run-merged packed bf16 atomics.
#define EF_S 136
#define EF_QS 264
#define EF_MS 136
__global__ __launch_bounds__(256, 6) void k_edge_fused(
    unsigned char* __restrict__ he8, const unsigned char* __restrict__ R,
    const float* __restrict__ dist_s,
    const int* __restrict__ srcs, const int* __restrict__ dsts,
    const unsigned char* __restrict__ W1T, const float* __restrict__ W_eu,
    const float* __restrict__ b_eu,
    const unsigned char* __restrict__ W2T, const float* __restrict__ b_msg,
    unsigned short* __restrict__ agg) {
    __shared__ __align__(16) unsigned char s_A[32 * EF_S];
    __shared__ __align__(16) unsigned char s_Pd[32 * EF_S];
    __shared__ __align__(16) unsigned char s_Ph[32 * EF_S];
    __shared__ __align__(16) unsigned char s_Q[32 * EF_QS];
    __shared__ __align__(16) unsigned char s_msg[32 * EF_MS];
    __shared__ float s_dist[32];
    __shared__ int s_dsti[32];
    int t = threadIdx.x;
    int eb = blockIdx.x * 32;
    int row = t >> 3, sb = t & 7;
    int sid = srcs[eb + row];
    int did = dsts[eb + row];
    if (t < 32) {
        s_dsti[t] = dsts[eb + t];
        s_dist[t] = dist_s[eb + t];
    }
    *(uint4*)&s_A[row * EF_S + sb * 16] =
        *(const uint4*)(he8 + (size_t)(eb + row) * 128 + sb * 16);
    *(uint4*)&s_Ph[row * EF_S + sb * 16] =
        *(const uint4*)(R + (size_t)sid * 512 + sb * 16);
    *(uint4*)&s_Pd[row * EF_S + sb * 16] =
        *(const uint4*)(R + (size_t)did * 512 + 128 + sb * 16);
    {
        const uint4* qp = (const uint4*)(R + (size_t)sid * 512 + 256 + sb * 32);
        uint4 q0 = qp[0], q1 = qp[1];
        *(uint4*)&s_Q[row * EF_QS + sb * 32] = q0;
        *(uint4*)&s_Q[row * EF_QS + sb * 32 + 16] = q1;
    }
    int lane = t & 63, wv = t >> 6, quad = lane >> 4, l16 = lane & 15;
    int n0 = wv * 2;
    const unsigned char* B0 = W1T + (size_t)(n0 * 16 + l16) * 128 + quad * 8;
    ll64 Brg[4][2];
#pragma unroll
    for (int kk = 0; kk < 4; ++kk) {
        Brg[kk][0] = *(const ll64*)(B0 + kk * 32);
        Brg[kk][1] = *(const ll64*)(B0 + 2048 + kk * 32);
    }
    __syncthreads();

    v4f zero4 = {0.f, 0.f, 0.f, 0.f};
    v4f acc[2][2];
    acc[0][0] = zero4; acc[0][1] = zero4; acc[1][0] = zero4; acc[1][1] = zero4;
#pragma unroll
    for (int kk = 0; kk < 4; ++kk) {
        int ko = kk * 32 + quad * 8;
#pragma unroll
        for (int mt = 0; mt < 2; ++mt) {
            ll64 a = *(const ll64*)&s_A[(mt * 16 + l16) * EF_S + ko];
            acc[mt][0] = MFMA8(a, Brg[kk][0], acc[mt][0]);
            acc[mt][1] = MFMA8(a, Brg[kk][1], acc[mt][1]);
        }
    }
    // ---- edge epilogue: LDS writes only ----
#pragma unroll
    for (int nl = 0; nl < 2; ++nl) {
        int c = (n0 + nl) * 16 + l16;
        float w640 = W_eu[640 * 128 + c];
        float bb = b_eu[c];
#pragma unroll
        for (int mt = 0; mt < 2; ++mt)
#pragma unroll
            for (int rr = 0; rr < 2; ++rr) {
                int rw0 = mt * 16 + quad * 4 + rr * 2;
                int rw1 = rw0 + 1;
                float S0 = (dec1(s_Ph[rw0 * EF_S + c]) +
                            dec1(s_Pd[rw0 * EF_S + c])) * AINV;
                float S1 = (dec1(s_Ph[rw1 * EF_S + c]) +
                            dec1(s_Pd[rw1 * EF_S + c])) * AINV;
                float v0 = fmaxf(acc[mt][nl][rr * 2] * INV_S + S0 +
                                 s_dist[rw0] * w640 + bb, 0.f);
                float v1 = fmaxf(acc[mt][nl][rr * 2 + 1] * INV_S + S1 +
                                 s_dist[rw1] * w640 + bb, 0.f);
                unsigned pk = encpk(ASCL * v0, ASCL * v1);
                s_Ph[rw0 * EF_S + c] = (unsigned char)(pk & 255u);
                s_Ph[rw1 * EF_S + c] = (unsigned char)(pk >> 8);
            }
    }
    __syncthreads();
    // ---- cooperative he8 write-back: one uint4 store per thread ----
    *(uint4*)(he8 + (size_t)(eb + row) * 128 + sb * 16) =
        *(const uint4*)&s_Ph[row * EF_S + sb * 16];

    // ---- msg GEMM: 2 M-tiles x 4 N-tiles, K=128 over he_new ----
    v4f mac[2][4];
#pragma unroll
    for (int nl = 0; nl < 4; ++nl) { mac[0][nl] = zero4; mac[1][nl] = zero4; }
    int q0n = wv * 4;
#pragma unroll
    for (int kk = 0; kk < 4; ++kk) {
        int ko = kk * 32 + quad * 8;
        ll64 b[4];
#pragma unroll
        for (int nl = 0; nl < 4; ++nl)
            b[nl] = *(const ll64*)(W2T + (size_t)((q0n + nl) * 16 + l16) * 128 + ko);
#pragma unroll
        for (int mt = 0; mt < 2; ++mt) {
            ll64 a = *(const ll64*)&s_Ph[(mt * 16 + l16) * EF_S + ko];
#pragma unroll
            for (int nl = 0; nl < 4; ++nl) mac[mt][nl] = MFMA8(a, b[nl], mac[mt][nl]);
        }
    }
    // ---- msg epilogue: + Q + bias, relu -> fp8 into s_msg ----
#pragma unroll
    for (int nl = 0; nl < 4; ++nl) {
        int c = (q0n + nl) * 16 + l16;
        float bm = b_msg[c];
#pragma unroll
        for (int mt = 0; mt < 2; ++mt)
#pragma unroll
            for (int rr = 0; rr < 2; ++rr) {
                int rw0 = mt * 16 + quad * 4 + rr * 2;
                int rw1 = rw0 + 1;
                float q0v = dec1(s_Q[rw0 * EF_QS + c]) * AINV;
                float q1v = dec1(s_Q[rw1 * EF_QS + c]) * AINV;
                float v0 = fmaxf(mac[mt][nl][rr * 2] * INV_S + q0v + bm, 0.f);
                float v1 = fmaxf(mac[mt][nl][rr * 2 + 1] * INV_S + q1v + bm, 0.f);
                unsigned pk = encpk(ASCL * v0, ASCL * v1);
                s_msg[rw0 * EF_MS + c] = (unsigned char)(pk & 255u);
                s_msg[rw1 * EF_MS + c] = (unsigned char)(pk >> 8);
            }
    }
    __syncthreads();
    // ---- run-merged packed bf16 atomics (dst sorted within block) ----
    {
        int cp = t & 127;
        int half = t >> 7;
        int r0 = half * 16, r1 = r0 + 16;
        float ax = 0.f, ay = 0.f;
        int cur = s_dsti[r0];
        for (int rw = r0; rw < r1; ++rw) {
            int d2 = s_dsti[rw];
            if (d2 != cur) {
                if (ax != 0.f || ay != 0.f) {
                    __hip_bfloat162 pv;
                    pv.x = __float2bfloat16(ax * AINV);
                    pv.y = __float2bfloat16(ay * AINV);
                    unsafeAtomicAdd((__hip_bfloat162*)&agg[(size_t)cur * 256 + cp * 2], pv);
                }
                ax = 0.f; ay = 0.f; cur = d2;
            }
            unsigned short v = *(const unsigned short*)&s_msg[rw * EF_MS + cp * 2];
            ax += dec1(v & 255u);
            ay += dec1(v >> 8);
        }
        if (ax != 0.f || ay != 0.f) {
            __hip_bfloat162 pv;
            pv.x = __float2bfloat16(ax * AINV);
            pv.y = __float2bfloat16(ay * AINV);
            unsafeAtomicAdd((__hip_bfloat162*)&agg[(size_t)cur * 256 + cp * 2], pv);
        }
    }
}

// ---------- fused node update + next-layer precompute -----------------------
// GEMM1: hn_new = hn + relu([hn|agg]@W_nu + b)   (K=512)
// GEMM2 (if do_pre): R = hn_new @ WpreT_next      (K=256, N=512)
// Epilogues -> LDS; cooperative vectorized write-back for hn8 and R.
#define NF_AS 520
#define NF_BS 264
__global__ __launch_bounds__(256, 3) void k_node_fused(
    unsigned char* __restrict__ hn8, const unsigned short* __restrict__ agg,
    const unsigned char* __restrict__ WnuT, const float* __restrict__ b,
    const unsigned char* __restrict__ WpreT, unsigned char* __restrict__ R,
    int do_pre) {
    __shared__ unsigned char s_A[64 * NF_AS];  // [hn|agg] then GEMM2 output
    __shared__ unsigned char s_B[64 * NF_BS];  // hn_new
    int t = threadIdx.x;
    int rb = blockIdx.x * 64;
    int row4 = t >> 2, sb4 = t & 3;
    {
        int gr = rb + row4; if (gr >= NN) gr = NN - 1;
        const uint4* sp = (const uint4*)(hn8 + (size_t)gr * 256 + sb4 * 64);
        uint4 a = sp[0], b2 = sp[1], c = sp[2], d = sp[3];
        uint4* dp = (uint4*)&s_A[row4 * NF_AS + sb4 * 64];
        dp[0] = a; dp[1] = b2; dp[2] = c; dp[3] = d;
        const unsigned short* ap = agg + (size_t)gr * 256 + sb4 * 64;
        unsigned char* dq = &s_A[row4 * NF_AS + 256 + sb4 * 64];
#pragma unroll
        for (int j = 0; j < 64; j += 2) {
            unsigned pk = encpk(ASCL * bf_f(ap[j]), ASCL * bf_f(ap[j + 1]));
            *(unsigned short*)&dq[j] = (unsigned short)pk;
        }
    }
    __syncthreads();
    int lane = t & 63, wv = t >> 6, quad = lane >> 4, l16 = lane & 15;
    v4f zero4 = {0.f, 0.f, 0.f, 0.f};
    {
        v4f acc[4][4];
#pragma unroll
        for (int mt = 0; mt < 4; ++mt)
#pragma unroll
            for (int nl = 0; nl < 4; ++nl) acc[mt][nl] = zero4;
        int q0 = wv * 4;
#pragma unroll 2
        for (int k = 0; k < 512; k += 32) {
            int ko = k + quad * 8;
            ll64 b2[4];
#pragma unroll
            for (int nl = 0; nl < 4; ++nl)
                b2[nl] = *(const ll64*)(WnuT + (size_t)((q0 + nl) * 16 + l16) * 512 + ko);
#pragma unroll
            for (int mt = 0; mt < 4; ++mt) {
                ll64 a = *(const ll64*)&s_A[(mt * 16 + l16) * NF_AS + ko];
#pragma unroll
                for (int nl = 0; nl < 4; ++nl) acc[mt][nl] = MFMA8(a, b2[nl], acc[mt][nl]);
            }
        }
#pragma unroll
        for (int nl = 0; nl < 4; ++nl) {
            int c = (q0 + nl) * 16 + l16;
            float bv = b[c];
#pragma unroll
            for (int mt = 0; mt < 4; ++mt)
#pragma unroll
                for (int rr = 0; rr < 2; ++rr) {
                    int rw0 = mt * 16 + quad * 4 + rr * 2;
                    float o0 = dec1(s_A[rw0 * NF_AS + c]) * AINV;
                    float o1 = dec1(s_A[(rw0 + 1) * NF_AS + c]) * AINV;
                    float v0 = o0 + fmaxf(acc[mt][nl][rr * 2] * INV_S + bv, 0.f);
                    float v1 = o1 + fmaxf(acc[mt][nl][rr * 2 + 1] * INV_S + bv, 0.f);
                    unsigned pk = encpk(ASCL * v0, ASCL * v1);
                    s_B[rw0 * NF_BS + c] = (unsigned char)(pk & 255u);
                    s_B[(rw0 + 1) * NF_BS + c] = (unsigned char)(pk >> 8);
                }
        }
    }
    __syncthreads();
    // ---- cooperative hn8 write-back: 4 uint4 stores per thread ----
    if (rb + row4 < NN) {
        const unsigned char* sp = &s_B[row4 * NF_BS + sb4 * 64];
        uint4* dp = (uint4*)(hn8 + (size_t)(rb + row4) * 256 + sb4 * 64);
        dp[0] = *(const uint4*)(sp);
        dp[1] = *(const uint4*)(sp + 16);
        dp[2] = *(const uint4*)(sp + 32);
        dp[3] = *(const uint4*)(sp + 48);
    }
    if (!do_pre) return;
    // ---- GEMM2: R = hn_new @ WpreT (K=256, N=512), output into s_A ----
#pragma unroll
    for (int pass = 0; pass < 2; ++pass) {
        int nt0 = wv * 8 + pass * 4;
        v4f acc[4][4];
#pragma unroll
        for (int mt = 0; mt < 4; ++mt)
#pragma unroll
            for (int nl = 0; nl < 4; ++nl) acc[mt][nl] = zero4;
#pragma unroll 2
        for (int k = 0; k < 256; k += 32) {
            int ko = k + quad * 8;
            ll64 b2[4];
#pragma unroll
            for (int nl = 0; nl < 4; ++nl)
                b2[nl] = *(const ll64*)(WpreT + (size_t)((nt0 + nl) * 16 + l16) * 256 + ko);
#pragma unroll
            for (int mt = 0; mt < 4; ++mt) {
                ll64 a = *(const ll64*)&s_B[(mt * 16 + l16) * NF_BS + ko];
#pragma unroll
                for (int nl = 0; nl < 4; ++nl) acc[mt][nl] = MFMA8(a, b2[nl], acc[mt][nl]);
            }
        }
#pragma unroll
        for (int nl = 0; nl < 4; ++nl) {
            int c = (nt0 + nl) * 16 + l16;
#pragma unroll
            for (int mt = 0; mt < 4; ++mt)
#pragma unroll
                for (int rr = 0; rr < 2; ++rr) {
                    int rw0 = mt * 16 + quad * 4 + rr * 2;
                    unsigned pk = encpk(acc[mt][nl][rr * 2] * 0.00390625f,
                                        acc[mt][nl][rr * 2 + 1] * 0.00390625f);
                    s_A[rw0 * NF_AS + c] = (unsigned char)(pk & 255u);
                    s_A[(rw0 + 1) * NF_AS + c] = (unsigned char)(pk >> 8);
                }
        }
    }
    __syncthreads();
    // ---- cooperative R write-back: 8 uint4 stores per thread ----
    if (rb + row4 < NN) {
        const unsigned char* sp = &s_A[row4 * NF_AS + sb4 * 128];
        uint4* dp = (uint4*)(R + (size_t)(rb + row4) * 512 + sb4 * 128);
#pragma unroll
        for (int j = 0; j < 8; ++j) dp[j] = *(const uint4*)(sp + j * 16);
    }
}

// ---------- pooling + final MLP (wave-cooperative row reads) ----------------
__device__ __forceinline__ int lbound(const void* a, int n, int v, int is64) {
    int lo = 0, hi = n;
    while (lo < hi) {
        int mid = (lo + hi) >> 1;
        if (IDX(a, mid, is64) < v) lo = mid + 1; else hi = mid;
    }
    return lo;
}

__global__ __launch_bounds__(512) void k_pool_mlp(
    const unsigned char* __restrict__ hn8, const unsigned char* __restrict__ he8,
    const int* __restrict__ inv,
    const void* __restrict__ bn, const void* __restrict__ be,
    const int* __restrict__ flag,
    const float* __restrict__ Wf1, const float* __restrict__ bf1,
    const float* __restrict__ Wf2, const float* __restrict__ bf2,
    float* __restrict__ out) {
    __shared__ float s_nacc[8][256];
    __shared__ float s_eacc[16][128];
    __shared__ float s_sub[384];
    __shared__ float s_hid[512];
    int b = blockIdx.x;
    int t = threadIdx.x;
    int is64 = *flag;
    int lane = t & 63, wv = t >> 6;
    int nlo = lbound(bn, NN, b, is64), nhi = lbound(bn, NN, b + 1, is64);
    int elo = lbound(be, NE, b, is64), ehi = lbound(be, NE, b + 1, is64);
    {
        float a0 = 0.f, a1 = 0.f, a2 = 0.f, a3 = 0.f;
        for (int i = nlo + wv; i < nhi; i += 8) {
            unsigned u = *(const unsigned*)(hn8 + (size_t)i * 256 + lane * 4);
            a0 += dec1(u & 255u);
            a1 += dec1((u >> 8) & 255u);
            a2 += dec1((u >> 16) & 255u);
            a3 += dec1(u >> 24);
        }
        s_nacc[wv][lane * 4 + 0] = a0;
        s_nacc[wv][lane * 4 + 1] = a1;
        s_nacc[wv][lane * 4 + 2] = a2;
        s_nacc[wv][lane * 4 + 3] = a3;
    }
    {
        int g16 = wv * 2 + (lane >> 5);
        int sl = lane & 31;
        float a0 = 0.f, a1 = 0.f, a2 = 0.f, a3 = 0.f;
        for (int e = elo + g16; e < ehi; e += 16) {
            int row = inv[e];
            unsigned u = *(const unsigned*)(he8 + (size_t)row * 128 + sl * 4);
            a0 += dec1(u & 255u);
            a1 += dec1((u >> 8) & 255u);
            a2 += dec1((u >> 16) & 255u);
            a3 += dec1(u >> 24);
        }
        s_eacc[g16][sl * 4 + 0] = a0;
        s_eacc[g16][sl * 4 + 1] = a1;
        s_eacc[g16][sl * 4 + 2] = a2;
        s_eacc[g16][sl * 4 + 3] = a3;
    }
    __syncthreads();
    if (t < 256) {
        float s = 0.f;
#pragma unroll
        for (int w = 0; w < 8; ++w) s += s_nacc[w][t];
        s_sub[t] = s * AINV / fmaxf((float)(nhi - nlo), 1.f);
    } else if (t < 384) {
        int c = t - 256;
        float s = 0.f;
#pragma unroll
        for (int j = 0; j < 16; ++j) s += s_eacc[j][c];
        s_sub[t] = s * AINV / fmaxf((float)(ehi - elo), 1.f);
    }
    __syncthreads();
    float hacc = bf1[t];
    for (int k = 0; k < 384; ++k) hacc += s_sub[k] * Wf1[k * 512 + t];
    s_hid[t] = fmaxf(hacc, 0.f);
    __syncthreads();
    if (t < 256) {
        float o = bf2[t];
        for (int k = 0; k < 512; ++k) o += s_hid[k] * Wf2[k * 256 + t];
        out[(size_t)b * 256 + t] = o;
    }
}

// ---------- second output ---------------------------------------------------
__global__ __launch_bounds__(256) void k_write_batch(const void* __restrict__ bn,
                                                     const int* __restrict__ flag,
                                                     float* __restrict__ out) {
    int i = blockIdx.x * 256 + threadIdx.x;
    if (i < NN) out[(size_t)NB * 256 + i] = (float)IDX(bn, i, *flag);
}

__global__ __launch_bounds__(256) void k_fill(float* __restrict__ p, int n, float v) {
    int i = blockIdx.x * 256 + threadIdx.x;
    if (i < n) p[i] = v;
}

extern "C" void kernel_launch(void* const* d_in, const int* in_sizes, int n_in,
                              void* d_out, int out_size, void* d_ws, size_t ws_size,
                              hipStream_t stream) {
    const float* h_node = (const float*)d_in[0];
    const float* pos    = (const float*)d_in[1];
    const float* h_edge = (const float*)d_in[2];
    const float* W_node = (const float*)d_in[3];
    const float* W_edge = (const float*)d_in[4];
    const float* W_eu   = (const float*)d_in[5];
    const float* b_eu   = (const float*)d_in[6];
    const float* W_msg  = (const float*)d_in[7];
    const float* b_msg  = (const float*)d_in[8];
    const float* W_nu   = (const float*)d_in[9];
    const float* b_nu   = (const float*)d_in[10];
    const float* Wf1    = (const float*)d_in[11];
    const float* bf1    = (const float*)d_in[12];
    const float* Wf2    = (const float*)d_in[13];
    const float* bf2    = (const float*)d_in[14];
    const void* ei = d_in[15];
    const void* bn = d_in[16];
    const void* be = d_in[17];

    float* out = (float*)d_out;

    const size_t SZ_FLAG = 256;
    const size_t SZ_HN   = (size_t)NN * 256;
    const size_t SZ_HE   = (size_t)NE * 128;
    const size_t SZ_AGG  = (size_t)NN * 256 * 2;
    const size_t SZ_R    = (size_t)NN * 512;
    const size_t SZ_PERM = (size_t)NE * 4;
    const size_t SZ_INV  = (size_t)NE * 4;
    const size_t SZ_SRC  = (size_t)NE * 4;
    const size_t SZ_DST  = (size_t)NE * 4;
    const size_t SZ_DS   = (size_t)NE * 4;
    const size_t SZ_PTR  = 512 * 1024;
    const size_t SZ_CUR  = 512 * 1024;
    const size_t SZ_W1   = (size_t)3 * 128 * 128;
    const size_t SZ_W2   = (size_t)3 * 256 * 128;
    const size_t SZ_WNU  = (size_t)3 * 256 * 512;
    const size_t SZ_WPRE = (size_t)3 * 512 * 256;
    const size_t NEED = SZ_FLAG + SZ_HN + SZ_HE + SZ_AGG + SZ_R + SZ_PERM +
                        SZ_INV + SZ_SRC + SZ_DST + SZ_DS + SZ_PTR + SZ_CUR +
                        SZ_W1 + SZ_W2 + SZ_WNU + SZ_WPRE;  // ~225 MB

    char* ws = (char*)d_ws;
    int* flag = (int*)ws;                       ws += SZ_FLAG;
    unsigned char* hn8 = (unsigned char*)ws;    ws += SZ_HN;
    unsigned char* he8 = (unsigned char*)ws;    ws += SZ_HE;
    unsigned short* agg = (unsigned short*)ws;  ws += SZ_AGG;
    unsigned char* R = (unsigned char*)ws;      ws += SZ_R;
    int* perm = (int*)ws;                       ws += SZ_PERM;
    int* inv = (int*)ws;                        ws += SZ_INV;
    int* srcs = (int*)ws;                       ws += SZ_SRC;
    int* dsts = (int*)ws;                       ws += SZ_DST;
    float* dist_s = (float*)ws;                 ws += SZ_DS;
    int* rowptr = (int*)ws;                     ws += SZ_PTR;
    int* cursor = (int*)ws;                     ws += SZ_CUR;
    unsigned char* W1T = (unsigned char*)ws;    ws += SZ_W1;
    unsigned char* W2T = (unsigned char*)ws;    ws += SZ_W2;
    unsigned char* WnuT = (unsigned char*)ws;   ws += SZ_WNU;
    unsigned char* WpreT = (unsigned char*)ws;  ws += SZ_WPRE;

    if (ws_size < NEED) {
        float enc = -(100000.0f + (float)(ws_size >> 20));
        k_detect<<<1, 64, 0, stream>>>((const int*)bn, flag);
        k_fill<<<(NB * 256 + 255) / 256, 256, 0, stream>>>(out, NB * 256, enc);
        k_write_batch<<<(NN + 255) / 256, 256, 0, stream>>>(bn, flag, out);
        return;
    }

    k_detect<<<1, 64, 0, stream>>>((const int*)bn, flag);
    k_tr_w1<<<(3 * 128 * 128 + 255) / 256, 256, 0, stream>>>(W_eu, W1T);
    k_tr_w2<<<(3 * 256 * 128 + 255) / 256, 256, 0, stream>>>(W_msg, W2T);
    k_tr_nu<<<(3 * 256 * 512 + 255) / 256, 256, 0, stream>>>(W_nu, WnuT);
    k_tr_pre<<<(3 * 512 * 256 + 255) / 256, 256, 0, stream>>>(W_eu, W_msg, WpreT);
    k_node_embed<<<NN / 8, 256, 0, stream>>>(h_node, W_node, hn8);

    hipMemsetAsync(cursor, 0, (size_t)NN * 4, stream);
    k_hist<<<(NE + 255) / 256, 256, 0, stream>>>(ei, flag, cursor);
    k_scan<<<1, 1024, 0, stream>>>(cursor, rowptr);
    hipMemcpyAsync(cursor, rowptr, (size_t)NN * 4, hipMemcpyDeviceToDevice, stream);
    k_perm<<<(NE + 255) / 256, 256, 0, stream>>>(ei, flag, pos, cursor, perm,
                                                 inv, srcs, dsts, dist_s);
    k_edge_embed<<<NE / 16, 256, 0, stream>>>(h_edge, W_edge, perm, he8);

    // initial R from embedded hn (layer 0 weights)
    k_node_pre<<<(NN + 63) / 64, 256, 0, stream>>>(hn8, WpreT, R);

    for (int l = 0; l < 3; ++l) {
        hipMemsetAsync(agg, 0, SZ_AGG, stream);
        k_edge_fused<<<NE / 32, 256, 0, stream>>>(
            he8, R, dist_s, srcs, dsts,
            W1T + (size_t)l * 128 * 128, W_eu + (size_t)l * 641 * 128,
            b_eu + (size_t)l * 128,
            W2T + (size_t)l * 256 * 128, b_msg + (size_t)l * 256, agg);
        int do_pre = (l < 2) ? 1 : 0;
        const unsigned char* wpre_next = WpreT + (size_t)(do_pre ? (l + 1) : 0) * 512 * 256;
        k_node_fused<<<(NN + 63) / 64, 256, 0, stream>>>(
            hn8, agg, WnuT + (size_t)l * 256 * 512, b_nu + (size_t)l * 256,
            wpre_next, R, do_pre);
    }

    k_pool_mlp<<<NB, 512, 0, stream>>>(hn8, he8, inv, bn, be, flag,
                                       Wf1, bf1, Wf2, bf2, out);
    k_write_batch<<<(NN + 255) / 256, 256, 0, stream>>>(bn, flag, out);
}

// Round 13
// 1704.298 us; speedup vs baseline: 1.1331x; 1.0176x over previous
//
#include <hip/hip_runtime.h>
#include <hip/hip_bf16.h>
#include <math.h>

#define NN 100000
#define NE 640000
#define NB 2000

typedef __attribute__((ext_vector_type(4))) float v4f;
typedef __attribute__((ext_vector_type(2))) float v2f;
typedef long long ll64;
#define MFMA8(a, b, c) __builtin_amdgcn_mfma_f32_16x16x32_fp8_fp8(a, b, c, 0, 0, 0)

// scales: activations x16, weights x256, accum de-scale 1/4096
#define INV_S 0.000244140625f
#define ASCL 16.0f
#define AINV 0.0625f

#if __has_builtin(__builtin_amdgcn_cvt_pk_fp8_f32) && __has_builtin(__builtin_amdgcn_cvt_f32_fp8)
#define HW_FP8 1
#else
#define HW_FP8 0
#endif
#if __has_builtin(__builtin_amdgcn_cvt_pk_f32_fp8)
#define HW_PK8 1
#else
#define HW_PK8 0
#endif

// ---------- int32/int64 index handling --------------------------------------
__device__ __forceinline__ int IDX(const void* p, size_t i, int is64) {
    return is64 ? (int)((const long long*)p)[i] : ((const int*)p)[i];
}
__device__ __forceinline__ int clampi(int v, int n) {
    return ((unsigned)v < (unsigned)n) ? v : 0;
}

__global__ void k_detect(const int* bn32, int* flag) {
    if (threadIdx.x == 0 && blockIdx.x == 0) {
        int is64 = 1;
        for (int k = 50001; k < 50401; k += 2)
            if (bn32[k] != 0) { is64 = 0; break; }
        *flag = is64;
    }
}

// ---------- fp8 e4m3 codec: HW cvt on gfx950, software fallback -------------
__device__ __forceinline__ unsigned sw_enc_fp8(float x) {
    unsigned s = (__float_as_uint(x) >> 24) & 0x80u;
    float ax = fminf(fabsf(x), 448.f);
    if (ax < 0.015625f) {
        unsigned m = (unsigned)(ax * 512.f + 0.5f);
        return s | m;
    }
    unsigned b = __float_as_uint(ax) + 0x00080000u;
    unsigned e = (b >> 23) - 120u;
    unsigned m = (b >> 20) & 7u;
    unsigned v = (e << 3) | m;
    if (v > 0x7Eu) v = 0x7Eu;
    return s | v;
}
__device__ __forceinline__ float sw_dec_fp8(unsigned b) {
    unsigned s = (b & 0x80u) << 24;
    unsigned e = (b >> 3) & 15u;
    unsigned m = b & 7u;
    if (e) return __uint_as_float(s | ((e + 120u) << 23) | (m << 20));
    float f = (float)m * 0.001953125f;
    return (b & 0x80u) ? -f : f;
}
__device__ __forceinline__ unsigned enc1(float x) {
#if HW_FP8
    return (unsigned)__builtin_amdgcn_cvt_pk_fp8_f32(x, x, 0, false) & 255u;
#else
    return sw_enc_fp8(x);
#endif
}
__device__ __forceinline__ unsigned encpk(float a, float b) {
#if HW_FP8
    return (unsigned)__builtin_amdgcn_cvt_pk_fp8_f32(a, b, 0, false) & 0xFFFFu;
#else
    return sw_enc_fp8(a) | (sw_enc_fp8(b) << 8);
#endif
}
__device__ __forceinline__ float dec1(unsigned b) {
#if HW_FP8
    return __builtin_amdgcn_cvt_f32_fp8((int)b, 0);
#else
    return sw_dec_fp8(b);
#endif
}
// paired decode of 2 fp8 bytes in low 16 bits of v
__device__ __forceinline__ void dec2(unsigned v, float& a, float& b) {
#if HW_PK8
    v2f d = __builtin_amdgcn_cvt_pk_f32_fp8((int)(v & 0xFFFFu), false);
    a = d.x; b = d.y;
#else
    a = dec1(v & 255u); b = dec1((v >> 8) & 255u);
#endif
}
__device__ __forceinline__ float bf_f(unsigned short u) {
    return __uint_as_float((unsigned)u << 16);
}

// ---------- node type embed -------------------------------------------------
__global__ __launch_bounds__(256) void k_node_embed(const float* __restrict__ h_node,
                                                    const float* __restrict__ W,
                                                    unsigned char* __restrict__ hn8) {
    __shared__ float sh[8][16];
    int t = threadIdx.x;
    int r0 = blockIdx.x * 8;
    if (t < 128) sh[t >> 4][t & 15] = h_node[r0 * 16 + t];
    float w[16];
#pragma unroll
    for (int k = 0; k < 16; ++k) w[k] = W[k * 256 + t];
    __syncthreads();
#pragma unroll
    for (int r = 0; r < 8; ++r) {
        float acc = 0.f;
#pragma unroll
        for (int k = 0; k < 16; ++k) acc += sh[r][k] * w[k];
        hn8[(size_t)(r0 + r) * 256 + t] = (unsigned char)enc1(ASCL * acc);
    }
}

// ---------- edge type embed: write he8 in dst-sorted slot order -------------
__global__ __launch_bounds__(256) void k_edge_embed(const float* __restrict__ h_edge,
                                                    const float* __restrict__ W,
                                                    const int* __restrict__ perm,
                                                    unsigned char* __restrict__ he8) {
    __shared__ float sh[16][5];
    int t = threadIdx.x;
    int e0 = blockIdx.x * 16;
    if (t < 80) {
        int row = t / 5, col = t % 5;
        int e = perm[e0 + row];
        sh[row][col] = h_edge[(size_t)e * 5 + col];
    }
    int c = t & 127;
    int es = t >> 7;
    float w[5];
#pragma unroll
    for (int k = 0; k < 5; ++k) w[k] = W[k * 128 + c];
    __syncthreads();
#pragma unroll
    for (int e = 0; e < 8; ++e) {
        int ee = es * 8 + e;
        float acc = 0.f;
#pragma unroll
        for (int k = 0; k < 5; ++k) acc += sh[ee][k] * w[k];
        he8[(size_t)(e0 + ee) * 128 + c] = (unsigned char)enc1(ASCL * acc);
    }
}

// ---------- weight transposes (fp8, x256) -----------------------------------
__global__ __launch_bounds__(256) void k_tr_w1(const float* __restrict__ W,
                                               unsigned char* __restrict__ WT) {
    int i = blockIdx.x * 256 + threadIdx.x;
    if (i >= 3 * 128 * 128) return;
    int l = i / 16384, r = i % 16384;
    int n = r / 128, k = r % 128;
    WT[i] = (unsigned char)enc1(256.f * W[(size_t)l * 641 * 128 + (size_t)k * 128 + n]);
}
__global__ __launch_bounds__(256) void k_tr_w2(const float* __restrict__ W,
                                               unsigned char* __restrict__ WT) {
    int i = blockIdx.x * 256 + threadIdx.x;
    if (i >= 3 * 256 * 128) return;
    int l = i / 32768, r = i % 32768;
    int n = r / 128, k = r % 128;
    WT[i] = (unsigned char)enc1(256.f * W[(size_t)l * 384 * 256 + (size_t)(256 + k) * 256 + n]);
}
__global__ __launch_bounds__(256) void k_tr_nu(const float* __restrict__ W,
                                               unsigned char* __restrict__ WT) {
    int i = blockIdx.x * 256 + threadIdx.x;
    if (i >= 3 * 256 * 512) return;
    int l = i / 131072, r = i % 131072;
    int n = r / 512, k = r % 512;
    WT[i] = (unsigned char)enc1(256.f * W[(size_t)l * 512 * 256 + (size_t)k * 256 + n]);
}
// WpreT[l][n][k] n<512,k<256 : [Psrc | Pdst | Q] weight blocks
__global__ __launch_bounds__(256) void k_tr_pre(const float* __restrict__ Weu,
                                                const float* __restrict__ Wmsg,
                                                unsigned char* __restrict__ WT) {
    int i = blockIdx.x * 256 + threadIdx.x;
    if (i >= 3 * 512 * 256) return;
    int l = i / 131072, r = i % 131072;
    int n = r / 256, k = r % 256;
    float w;
    if (n < 128)      w = Weu[(size_t)l * 641 * 128 + (size_t)(128 + k) * 128 + n];
    else if (n < 256) w = Weu[(size_t)l * 641 * 128 + (size_t)(384 + k) * 128 + (n - 128)];
    else              w = Wmsg[(size_t)l * 384 * 256 + (size_t)k * 256 + (n - 256)];
    WT[i] = (unsigned char)enc1(256.f * w);
}
// final MLP weights: Wf1T [512][384], Wf2T [256][512]
__global__ __launch_bounds__(256) void k_tr_f1(const float* __restrict__ W,
                                               unsigned char* __restrict__ WT) {
    int i = blockIdx.x * 256 + threadIdx.x;
    if (i >= 512 * 384) return;
    int n = i / 384, k = i % 384;
    WT[i] = (unsigned char)enc1(256.f * W[(size_t)k * 512 + n]);
}
__global__ __launch_bounds__(256) void k_tr_f2(const float* __restrict__ W,
                                               unsigned char* __restrict__ WT) {
    int i = blockIdx.x * 256 + threadIdx.x;
    if (i >= 256 * 512) return;
    int n = i / 512, k = i % 512;
    WT[i] = (unsigned char)enc1(256.f * W[(size_t)k * 256 + n]);
}

// ---------- dst-sorted edge permutation (built once) ------------------------
__global__ __launch_bounds__(256) void k_hist(const void* __restrict__ ei,
                                              const int* __restrict__ flag,
                                              int* __restrict__ hist) {
    int e = blockIdx.x * 256 + threadIdx.x;
    if (e >= NE) return;
    int d = clampi(IDX(ei, (size_t)NE + e, *flag), NN);
    atomicAdd(&hist[d], 1);
}
__global__ __launch_bounds__(1024) void k_scan(const int* __restrict__ hist,
                                               int* __restrict__ rowptr) {
    __shared__ int part[1024];
    int t = threadIdx.x;
    const int C = 98;
    int s = 0;
    for (int j = 0; j < C; ++j) {
        int i = t * C + j;
        if (i < NN) s += hist[i];
    }
    part[t] = s;
    __syncthreads();
    if (t == 0) {
        int run = 0;
        for (int i = 0; i < 1024; ++i) { int v = part[i]; part[i] = run; run += v; }
    }
    __syncthreads();
    int run = part[t];
    for (int j = 0; j < C; ++j) {
        int i = t * C + j;
        if (i < NN) { rowptr[i] = run; run += hist[i]; }
    }
}
__global__ __launch_bounds__(256) void k_perm(const void* __restrict__ ei,
                                              const int* __restrict__ flag,
                                              const float* __restrict__ pos,
                                              int* __restrict__ cursor,
                                              int* __restrict__ perm,
                                              int* __restrict__ inv,
                                              int* __restrict__ srcs,
                                              int* __restrict__ dsts,
                                              float* __restrict__ dist_s) {
    int e = blockIdx.x * 256 + threadIdx.x;
    if (e >= NE) return;
    int is64 = *flag;
    int s = clampi(IDX(ei, (size_t)e, is64), NN);
    int d = clampi(IDX(ei, (size_t)NE + e, is64), NN);
    int p = atomicAdd(&cursor[d], 1);
    perm[p] = e;
    inv[e] = p;
    srcs[p] = s;
    dsts[p] = d;
    float dx = pos[d * 3 + 0] - pos[s * 3 + 0];
    float dy = pos[d * 3 + 1] - pos[s * 3 + 1];
    float dz = pos[d * 3 + 2] - pos[s * 3 + 2];
    dist_s[p] = sqrtf(dx * dx + dy * dy + dz * dz);
}

// ---------- node-side precompute (initial layer only): R = hn @ WpreT -------
#define NP_AS 264
__global__ __launch_bounds__(256, 3) void k_node_pre(
    const unsigned char* __restrict__ hn8, const unsigned char* __restrict__ WpreT,
    unsigned char* __restrict__ R) {
    __shared__ unsigned char s_A[64 * NP_AS];
    int t = threadIdx.x;
    int rb = blockIdx.x * 64;
    {
        int row = t >> 2, sb = t & 3;
        int gr = rb + row; if (gr >= NN) gr = NN - 1;
        const uint4* sp = (const uint4*)(hn8 + (size_t)gr * 256 + sb * 64);
        uint4 a = sp[0], b = sp[1], c = sp[2], d = sp[3];
        uint4* dp = (uint4*)&s_A[row * NP_AS + sb * 64];
        dp[0] = a; dp[1] = b; dp[2] = c; dp[3] = d;
    }
    __syncthreads();
    int lane = t & 63, wv = t >> 6, quad = lane >> 4, l16 = lane & 15;
    v4f zero4 = {0.f, 0.f, 0.f, 0.f};
#pragma unroll
    for (int pass = 0; pass < 2; ++pass) {
        int nt0 = wv * 8 + pass * 4;
        v4f acc[4][4];
#pragma unroll
        for (int mt = 0; mt < 4; ++mt)
#pragma unroll
            for (int nl = 0; nl < 4; ++nl) acc[mt][nl] = zero4;
#pragma unroll 2
        for (int k = 0; k < 256; k += 32) {
            int ko = k + quad * 8;
            ll64 b[4];
#pragma unroll
            for (int nl = 0; nl < 4; ++nl)
                b[nl] = *(const ll64*)(WpreT + (size_t)((nt0 + nl) * 16 + l16) * 256 + ko);
#pragma unroll
            for (int mt = 0; mt < 4; ++mt) {
                ll64 a = *(const ll64*)&s_A[(mt * 16 + l16) * NP_AS + ko];
#pragma unroll
                for (int nl = 0; nl < 4; ++nl) acc[mt][nl] = MFMA8(a, b[nl], acc[mt][nl]);
            }
        }
#pragma unroll
        for (int nl = 0; nl < 4; ++nl) {
            int c = (nt0 + nl) * 16 + l16;
#pragma unroll
            for (int mt = 0; mt < 4; ++mt)
#pragma unroll
                for (int rr = 0; rr < 2; ++rr) {
                    int rw0 = mt * 16 + quad * 4 + rr * 2;
                    unsigned pk = encpk(acc[mt][nl][rr * 2] * 0.00390625f,
                                        acc[mt][nl][rr * 2 + 1] * 0.00390625f);
                    if (rb + rw0 < NN)
                        R[(size_t)(rb + rw0) * 512 + c] = (unsigned char)(pk & 255u);
                    if (rb + rw0 + 1 < NN)
                        R[(size_t)(rb + rw0 + 1) * 512 + c] = (unsigned char)(pk >> 8);
                }
        }
    }
}

// ---------- fused edge+msg kernel: 32 sorted edges/block, 4 waves -----------
#define EF_S 136
#define EF_QS 264
#define EF_MS 136
__global__ __launch_bounds__(256, 6) void k_edge_fused(
    unsigned char* __restrict__ he8, const unsigned char* __restrict__ R,
    const float* __restrict__ dist_s,
    const int* __restrict__ srcs, const int* __restrict__ dsts,
    const unsigned char* __restrict__ W1T, const float* __restrict__ W_eu,
    const float* __restrict__ b_eu,
    const unsigned char* __restrict__ W2T, const float* __restrict__ b_msg,
    unsigned short* __restrict__ agg) {
    __shared__ __align__(16) unsigned char s_A[32 * EF_S];
    __shared__ __align__(16) unsigned char s_Pd[32 * EF_S];
    __shared__ __align__(16) unsigned char s_Ph[32 * EF_S];
    __shared__ __align__(16) unsigned char s_Q[32 * EF_QS];
    __shared__ __align__(16) unsigned char s_msg[32 * EF_MS];
    __shared__ float s_dist[32];
    __shared__ int s_dsti[32];
    int t = threadIdx.x;
    int eb = blockIdx.x * 32;
    int row = t >> 3, sb = t & 7;
    int sid = srcs[eb + row];
    int did = dsts[eb + row];
    if (t < 32) {
        s_dsti[t] = dsts[eb + t];
        s_dist[t] = dist_s[eb + t];
    }
    *(uint4*)&s_A[row * EF_S + sb * 16] =
        *(const uint4*)(he8 + (size_t)(eb + row) * 128 + sb * 16);
    *(uint4*)&s_Ph[row * EF_S + sb * 16] =
        *(const uint4*)(R + (size_t)sid * 512 + sb * 16);
    *(uint4*)&s_Pd[row * EF_S + sb * 16] =
        *(const uint4*)(R + (size_t)did * 512 + 128 + sb * 16);
    {
        const uint4* qp = (const uint4*)(R + (size_t)sid * 512 + 256 + sb * 32);
        uint4 q0 = qp[0], q1 = qp[1];
        *(uint4*)&s_Q[row * EF_QS + sb * 32] = q0;
        *(uint4*)&s_Q[row * EF_QS + sb * 32 + 16] = q1;
    }
    int lane = t & 63, wv = t >> 6, quad = lane >> 4, l16 = lane & 15;
    int n0 = wv * 2;
    const unsigned char* B0 = W1T + (size_t)(n0 * 16 + l16) * 128 + quad * 8;
    ll64 Brg[4][2];
#pragma unroll
    for (int kk = 0; kk < 4; ++kk) {
        Brg[kk][0] = *(const ll64*)(B0 + kk * 32);
        Brg[kk][1] = *(const ll64*)(B0 + 2048 + kk * 32);
    }
    __syncthreads();

    v4f zero4 = {0.f, 0.f, 0.f, 0.f};
    v4f acc[2][2];
    acc[0][0] = zero4; acc[0][1] = zero4; acc[1][0] = zero4; acc[1][1] = zero4;
#pragma unroll
    for (int kk = 0; kk < 4; ++kk) {
        int ko = kk * 32 + quad * 8;
#pragma unroll
        for (int mt = 0; mt < 2; ++mt) {
            ll64 a = *(const ll64*)&s_A[(mt * 16 + l16) * EF_S + ko];
            acc[mt][0] = MFMA8(a, Brg[kk][0], acc[mt][0]);
            acc[mt][1] = MFMA8(a, Brg[kk][1], acc[mt][1]);
        }
    }
    // ---- edge epilogue: LDS writes only ----
#pragma unroll
    for (int nl = 0; nl < 2; ++nl) {
        int c = (n0 + nl) * 16 + l16;
        float w640 = W_eu[640 * 128 + c];
        float bb = b_eu[c];
#pragma unroll
        for (int mt = 0; mt < 2; ++mt)
#pragma unroll
            for (int rr = 0; rr < 2; ++rr) {
                int rw0 = mt * 16 + quad * 4 + rr * 2;
                int rw1 = rw0 + 1;
                float S0 = (dec1(s_Ph[rw0 * EF_S + c]) +
                            dec1(s_Pd[rw0 * EF_S + c])) * AINV;
                float S1 = (dec1(s_Ph[rw1 * EF_S + c]) +
                            dec1(s_Pd[rw1 * EF_S + c])) * AINV;
                float v0 = fmaxf(acc[mt][nl][rr * 2] * INV_S + S0 +
                                 s_dist[rw0] * w640 + bb, 0.f);
                float v1 = fmaxf(acc[mt][nl][rr * 2 + 1] * INV_S + S1 +
                                 s_dist[rw1] * w640 + bb, 0.f);
                unsigned pk = encpk(ASCL * v0, ASCL * v1);
                s_Ph[rw0 * EF_S + c] = (unsigned char)(pk & 255u);
                s_Ph[rw1 * EF_S + c] = (unsigned char)(pk >> 8);
            }
    }
    __syncthreads();
    // ---- cooperative he8 write-back ----
    *(uint4*)(he8 + (size_t)(eb + row) * 128 + sb * 16) =
        *(const uint4*)&s_Ph[row * EF_S + sb * 16];

    // ---- msg GEMM ----
    v4f mac[2][4];
#pragma unroll
    for (int nl = 0; nl < 4; ++nl) { mac[0][nl] = zero4; mac[1][nl] = zero4; }
    int q0n = wv * 4;
#pragma unroll
    for (int kk = 0; kk < 4; ++kk) {
        int ko = kk * 32 + quad * 8;
        ll64 b[4];
#pragma unroll
        for (int nl = 0; nl < 4; ++nl)
            b[nl] = *(const ll64*)(W2T + (size_t)((q0n + nl) * 16 + l16) * 128 + ko);
#pragma unroll
        for (int mt = 0; mt < 2; ++mt) {
            ll64 a = *(const ll64*)&s_Ph[(mt * 16 + l16) * EF_S + ko];
#pragma unroll
            for (int nl = 0; nl < 4; ++nl) mac[mt][nl] = MFMA8(a, b[nl], mac[mt][nl]);
        }
    }
    // ---- msg epilogue -> fp8 s_msg ----
#pragma unroll
    for (int nl = 0; nl < 4; ++nl) {
        int c = (q0n + nl) * 16 + l16;
        float bm = b_msg[c];
#pragma unroll
        for (int mt = 0; mt < 2; ++mt)
#pragma unroll
            for (int rr = 0; rr < 2; ++rr) {
                int rw0 = mt * 16 + quad * 4 + rr * 2;
                int rw1 = rw0 + 1;
                float q0v = dec1(s_Q[rw0 * EF_QS + c]) * AINV;
                float q1v = dec1(s_Q[rw1 * EF_QS + c]) * AINV;
                float v0 = fmaxf(mac[mt][nl][rr * 2] * INV_S + q0v + bm, 0.f);
                float v1 = fmaxf(mac[mt][nl][rr * 2 + 1] * INV_S + q1v + bm, 0.f);
                unsigned pk = encpk(ASCL * v0, ASCL * v1);
                s_msg[rw0 * EF_MS + c] = (unsigned char)(pk & 255u);
                s_msg[rw1 * EF_MS + c] = (unsigned char)(pk >> 8);
            }
    }
    __syncthreads();
    // ---- run-merged packed bf16 atomics (paired HW decode) ----
    {
        int cp = t & 127;
        int half = t >> 7;
        int r0 = half * 16, r1 = r0 + 16;
        float ax = 0.f, ay = 0.f;
        int cur = s_dsti[r0];
        for (int rw = r0; rw < r1; ++rw) {
            int d2 = s_dsti[rw];
            if (d2 != cur) {
                if (ax != 0.f || ay != 0.f) {
                    __hip_bfloat162 pv;
                    pv.x = __float2bfloat16(ax * AINV);
                    pv.y = __float2bfloat16(ay * AINV);
                    unsafeAtomicAdd((__hip_bfloat162*)&agg[(size_t)cur * 256 + cp * 2], pv);
                }
                ax = 0.f; ay = 0.f; cur = d2;
            }
            unsigned short v = *(const unsigned short*)&s_msg[rw * EF_MS + cp * 2];
            float f0, f1;
            dec2(v, f0, f1);
            ax += f0; ay += f1;
        }
        if (ax != 0.f || ay != 0.f) {
            __hip_bfloat162 pv;
            pv.x = __float2bfloat16(ax * AINV);
            pv.y = __float2bfloat16(ay * AINV);
            unsafeAtomicAdd((__hip_bfloat162*)&agg[(size_t)cur * 256 + cp * 2], pv);
        }
    }
}

// ---------- fused node update + next-layer precompute -----------------------
#define NF_AS 520
#define NF_BS 264
__global__ __launch_bounds__(256, 3) void k_node_fused(
    unsigned char* __restrict__ hn8, const unsigned short* __restrict__ agg,
    const unsigned char* __restrict__ WnuT, const float* __restrict__ b,
    const unsigned char* __restrict__ WpreT, unsigned char* __restrict__ R,
    int do_pre) {
    __shared__ unsigned char s_A[64 * NF_AS];
    __shared__ unsigned char s_B[64 * NF_BS];
    int t = threadIdx.x;
    int rb = blockIdx.x * 64;
    int row4 = t >> 2, sb4 = t & 3;
    {
        int gr = rb + row4; if (gr >= NN) gr = NN - 1;
        const uint4* sp = (const uint4*)(hn8 + (size_t)gr * 256 + sb4 * 64);
        uint4 a = sp[0], b2 = sp[1], c = sp[2], d = sp[3];
        uint4* dp = (uint4*)&s_A[row4 * NF_AS + sb4 * 64];
        dp[0] = a; dp[1] = b2; dp[2] = c; dp[3] = d;
        const unsigned short* ap = agg + (size_t)gr * 256 + sb4 * 64;
        unsigned char* dq = &s_A[row4 * NF_AS + 256 + sb4 * 64];
#pragma unroll
        for (int j = 0; j < 64; j += 2) {
            unsigned pk = encpk(ASCL * bf_f(ap[j]), ASCL * bf_f(ap[j + 1]));
            *(unsigned short*)&dq[j] = (unsigned short)pk;
        }
    }
    __syncthreads();
    int lane = t & 63, wv = t >> 6, quad = lane >> 4, l16 = lane & 15;
    v4f zero4 = {0.f, 0.f, 0.f, 0.f};
    {
        v4f acc[4][4];
#pragma unroll
        for (int mt = 0; mt < 4; ++mt)
#pragma unroll
            for (int nl = 0; nl < 4; ++nl) acc[mt][nl] = zero4;
        int q0 = wv * 4;
#pragma unroll 2
        for (int k = 0; k < 512; k += 32) {
            int ko = k + quad * 8;
            ll64 b2[4];
#pragma unroll
            for (int nl = 0; nl < 4; ++nl)
                b2[nl] = *(const ll64*)(WnuT + (size_t)((q0 + nl) * 16 + l16) * 512 + ko);
#pragma unroll
            for (int mt = 0; mt < 4; ++mt) {
                ll64 a = *(const ll64*)&s_A[(mt * 16 + l16) * NF_AS + ko];
#pragma unroll
                for (int nl = 0; nl < 4; ++nl) acc[mt][nl] = MFMA8(a, b2[nl], acc[mt][nl]);
            }
        }
#pragma unroll
        for (int nl = 0; nl < 4; ++nl) {
            int c = (q0 + nl) * 16 + l16;
            float bv = b[c];
#pragma unroll
            for (int mt = 0; mt < 4; ++mt)
#pragma unroll
                for (int rr = 0; rr < 2; ++rr) {
                    int rw0 = mt * 16 + quad * 4 + rr * 2;
                    float o0 = dec1(s_A[rw0 * NF_AS + c]) * AINV;
                    float o1 = dec1(s_A[(rw0 + 1) * NF_AS + c]) * AINV;
                    float v0 = o0 + fmaxf(acc[mt][nl][rr * 2] * INV_S + bv, 0.f);
                    float v1 = o1 + fmaxf(acc[mt][nl][rr * 2 + 1] * INV_S + bv, 0.f);
                    unsigned pk = encpk(ASCL * v0, ASCL * v1);
                    s_B[rw0 * NF_BS + c] = (unsigned char)(pk & 255u);
                    s_B[(rw0 + 1) * NF_BS + c] = (unsigned char)(pk >> 8);
                }
        }
    }
    __syncthreads();
    if (rb + row4 < NN) {
        const unsigned char* sp = &s_B[row4 * NF_BS + sb4 * 64];
        uint4* dp = (uint4*)(hn8 + (size_t)(rb + row4) * 256 + sb4 * 64);
        dp[0] = *(const uint4*)(sp);
        dp[1] = *(const uint4*)(sp + 16);
        dp[2] = *(const uint4*)(sp + 32);
        dp[3] = *(const uint4*)(sp + 48);
    }
    if (!do_pre) return;
#pragma unroll
    for (int pass = 0; pass < 2; ++pass) {
        int nt0 = wv * 8 + pass * 4;
        v4f acc[4][4];
#pragma unroll
        for (int mt = 0; mt < 4; ++mt)
#pragma unroll
            for (int nl = 0; nl < 4; ++nl) acc[mt][nl] = zero4;
#pragma unroll 2
        for (int k = 0; k < 256; k += 32) {
            int ko = k + quad * 8;
            ll64 b2[4];
#pragma unroll
            for (int nl = 0; nl < 4; ++nl)
                b2[nl] = *(const ll64*)(WpreT + (size_t)((nt0 + nl) * 16 + l16) * 256 + ko);
#pragma unroll
            for (int mt = 0; mt < 4; ++mt) {
                ll64 a = *(const ll64*)&s_B[(mt * 16 + l16) * NF_BS + ko];
#pragma unroll
                for (int nl = 0; nl < 4; ++nl) acc[mt][nl] = MFMA8(a, b2[nl], acc[mt][nl]);
            }
        }
#pragma unroll
        for (int nl = 0; nl < 4; ++nl) {
            int c = (nt0 + nl) * 16 + l16;
#pragma unroll
            for (int mt = 0; mt < 4; ++mt)
#pragma unroll
                for (int rr = 0; rr < 2; ++rr) {
                    int rw0 = mt * 16 + quad * 4 + rr * 2;
                    unsigned pk = encpk(acc[mt][nl][rr * 2] * 0.00390625f,
                                        acc[mt][nl][rr * 2 + 1] * 0.00390625f);
                    s_A[rw0 * NF_AS + c] = (unsigned char)(pk & 255u);
                    s_A[(rw0 + 1) * NF_AS + c] = (unsigned char)(pk >> 8);
                }
        }
    }
    __syncthreads();
    if (rb + row4 < NN) {
        const unsigned char* sp = &s_A[row4 * NF_AS + sb4 * 128];
        uint4* dp = (uint4*)(R + (size_t)(rb + row4) * 512 + sb4 * 128);
#pragma unroll
        for (int j = 0; j < 8; ++j) dp[j] = *(const uint4*)(sp + j * 16);
    }
}

// ---------- pooling means only (writes pooled bf16 [NB][384]) ---------------
__device__ __forceinline__ int lbound(const void* a, int n, int v, int is64) {
    int lo = 0, hi = n;
    while (lo < hi) {
        int mid = (lo + hi) >> 1;
        if (IDX(a, mid, is64) < v) lo = mid + 1; else hi = mid;
    }
    return lo;
}

__global__ __launch_bounds__(512) void k_pool_means(
    const unsigned char* __restrict__ hn8, const unsigned char* __restrict__ he8,
    const int* __restrict__ inv,
    const void* __restrict__ bn, const void* __restrict__ be,
    const int* __restrict__ flag,
    unsigned short* __restrict__ pooled) {
    __shared__ float s_nacc[8][256];
    __shared__ float s_eacc[16][128];
    int b = blockIdx.x;
    int t = threadIdx.x;
    int is64 = *flag;
    int lane = t & 63, wv = t >> 6;
    int nlo = lbound(bn, NN, b, is64), nhi = lbound(bn, NN, b + 1, is64);
    int elo = lbound(be, NE, b, is64), ehi = lbound(be, NE, b + 1, is64);
    {
        float a0 = 0.f, a1 = 0.f, a2 = 0.f, a3 = 0.f;
        for (int i = nlo + wv; i < nhi; i += 8) {
            unsigned u = *(const unsigned*)(hn8 + (size_t)i * 256 + lane * 4);
            float f0, f1, f2, f3;
            dec2(u, f0, f1);
            dec2(u >> 16, f2, f3);
            a0 += f0; a1 += f1; a2 += f2; a3 += f3;
        }
        s_nacc[wv][lane * 4 + 0] = a0;
        s_nacc[wv][lane * 4 + 1] = a1;
        s_nacc[wv][lane * 4 + 2] = a2;
        s_nacc[wv][lane * 4 + 3] = a3;
    }
    {
        int g16 = wv * 2 + (lane >> 5);
        int sl = lane & 31;
        float a0 = 0.f, a1 = 0.f, a2 = 0.f, a3 = 0.f;
        for (int e = elo + g16; e < ehi; e += 16) {
            int row = inv[e];
            unsigned u = *(const unsigned*)(he8 + (size_t)row * 128 + sl * 4);
            float f0, f1, f2, f3;
            dec2(u, f0, f1);
            dec2(u >> 16, f2, f3);
            a0 += f0; a1 += f1; a2 += f2; a3 += f3;
        }
        s_eacc[g16][sl * 4 + 0] = a0;
        s_eacc[g16][sl * 4 + 1] = a1;
        s_eacc[g16][sl * 4 + 2] = a2;
        s_eacc[g16][sl * 4 + 3] = a3;
    }
    __syncthreads();
    if (t < 256) {
        float s = 0.f;
#pragma unroll
        for (int w = 0; w < 8; ++w) s += s_nacc[w][t];
        float m = s * AINV / fmaxf((float)(nhi - nlo), 1.f);
        __hip_bfloat16 h = __float2bfloat16(m);
        pooled[(size_t)b * 384 + t] = *(unsigned short*)&h;
    } else if (t < 384) {
        int c = t - 256;
        float s = 0.f;
#pragma unroll
        for (int j = 0; j < 16; ++j) s += s_eacc[j][c];
        float m = s * AINV / fmaxf((float)(ehi - elo), 1.f);
        __hip_bfloat16 h = __float2bfloat16(m);
        pooled[(size_t)b * 384 + t] = *(unsigned short*)&h;
    }
}

// ---------- final MLP via fp8 MFMA: 64 graphs/block, 32 blocks --------------
#define FM_PS 392  // s_P row stride (384 + 8)
#define FM_HS 520  // s_H row stride (512 + 8)
__global__ __launch_bounds__(256, 1) void k_final(
    const unsigned short* __restrict__ pooled,
    const unsigned char* __restrict__ Wf1T, const float* __restrict__ bf1,
    const unsigned char* __restrict__ Wf2T, const float* __restrict__ bf2,
    float* __restrict__ out) {
    __shared__ unsigned char s_P[64 * FM_PS];  // 25.1 KB
    __shared__ unsigned char s_H[64 * FM_HS];  // 33.3 KB
    int t = threadIdx.x;
    int bb = blockIdx.x * 64;
    int row4 = t >> 2, sb4 = t & 3;
    {
        int g = bb + row4;
        unsigned char* dq = &s_P[row4 * FM_PS + sb4 * 96];
        if (g < NB) {
            const unsigned short* pr = pooled + (size_t)g * 384 + sb4 * 96;
#pragma unroll
            for (int j = 0; j < 12; ++j) {
                uint4 q = *(const uint4*)(pr + j * 8);
                unsigned w0, w1;
                {
                    unsigned p0 = encpk(ASCL * bf_f((unsigned short)(q.x & 0xFFFF)),
                                        ASCL * bf_f((unsigned short)(q.x >> 16)));
                    unsigned p1 = encpk(ASCL * bf_f((unsigned short)(q.y & 0xFFFF)),
                                        ASCL * bf_f((unsigned short)(q.y >> 16)));
                    w0 = p0 | (p1 << 16);
                    unsigned p2 = encpk(ASCL * bf_f((unsigned short)(q.z & 0xFFFF)),
                                        ASCL * bf_f((unsigned short)(q.z >> 16)));
                    unsigned p3 = encpk(ASCL * bf_f((unsigned short)(q.w & 0xFFFF)),
                                        ASCL * bf_f((unsigned short)(q.w >> 16)));
                    w1 = p2 | (p3 << 16);
                }
                *(unsigned*)(dq + j * 8) = w0;
                *(unsigned*)(dq + j * 8 + 4) = w1;
            }
        } else {
#pragma unroll
            for (int j = 0; j < 12; ++j) {
                *(unsigned*)(dq + j * 8) = 0;
                *(unsigned*)(dq + j * 8 + 4) = 0;
            }
        }
    }
    __syncthreads();
    int lane = t & 63, wv = t >> 6, quad = lane >> 4, l16 = lane & 15;
    v4f zero4 = {0.f, 0.f, 0.f, 0.f};
    // GEMM1: hidden = relu(P @ Wf1T + bf1)   M=64, N=512, K=384
#pragma unroll
    for (int pass = 0; pass < 2; ++pass) {
        int nt0 = wv * 8 + pass * 4;
        v4f acc[4][4];
#pragma unroll
        for (int mt = 0; mt < 4; ++mt)
#pragma unroll
            for (int nl = 0; nl < 4; ++nl) acc[mt][nl] = zero4;
        for (int k = 0; k < 384; k += 32) {
            int ko = k + quad * 8;
            ll64 b2[4];
#pragma unroll
            for (int nl = 0; nl < 4; ++nl)
                b2[nl] = *(const ll64*)(Wf1T + (size_t)((nt0 + nl) * 16 + l16) * 384 + ko);
#pragma unroll
            for (int mt = 0; mt < 4; ++mt) {
                ll64 a = *(const ll64*)&s_P[(mt * 16 + l16) * FM_PS + ko];
#pragma unroll
                for (int nl = 0; nl < 4; ++nl) acc[mt][nl] = MFMA8(a, b2[nl], acc[mt][nl]);
            }
        }
#pragma unroll
        for (int nl = 0; nl < 4; ++nl) {
            int c = (nt0 + nl) * 16 + l16;
            float bv = bf1[c];
#pragma unroll
            for (int mt = 0; mt < 4; ++mt)
#pragma unroll
                for (int rr = 0; rr < 2; ++rr) {
                    int rw0 = mt * 16 + quad * 4 + rr * 2;
                    float v0 = fmaxf(acc[mt][nl][rr * 2] * INV_S + bv, 0.f);
                    float v1 = fmaxf(acc[mt][nl][rr * 2 + 1] * INV_S + bv, 0.f);
                    unsigned pk = encpk(ASCL * v0, ASCL * v1);
                    s_H[rw0 * FM_HS + c] = (unsigned char)(pk & 255u);
                    s_H[(rw0 + 1) * FM_HS + c] = (unsigned char)(pk >> 8);
                }
        }
    }
    __syncthreads();
    // GEMM2: out = hidden @ Wf2T + bf2   M=64, N=256, K=512
    {
        v4f acc[4][4];
#pragma unroll
        for (int mt = 0; mt < 4; ++mt)
#pragma unroll
            for (int nl = 0; nl < 4; ++nl) acc[mt][nl] = zero4;
        int q0 = wv * 4;
        for (int k = 0; k < 512; k += 32) {
            int ko = k + quad * 8;
            ll64 b2[4];
#pragma unroll
            for (int nl = 0; nl < 4; ++nl)
                b2[nl] = *(const ll64*)(Wf2T + (size_t)((q0 + nl) * 16 + l16) * 512 + ko);
#pragma unroll
            for (int mt = 0; mt < 4; ++mt) {
                ll64 a = *(const ll64*)&s_H[(mt * 16 + l16) * FM_HS + ko];
#pragma unroll
                for (int nl = 0; nl < 4; ++nl) acc[mt][nl] = MFMA8(a, b2[nl], acc[mt][nl]);
            }
        }
#pragma unroll
        for (int nl = 0; nl < 4; ++nl) {
            int c = (q0 + nl) * 16 + l16;
            float bv = bf2[c];
#pragma unroll
            for (int mt = 0; mt < 4; ++mt)
#pragma unroll
                for (int r = 0; r < 4; ++r) {
                    int rw = mt * 16 + quad * 4 + r;
                    if (bb + rw < NB)
                        out[(size_t)(bb + rw) * 256 + c] = acc[mt][nl][r] * INV_S + bv;
                }
        }
    }
}

// ---------- second output ---------------------------------------------------
__global__ __launch_bounds__(256) void k_write_batch(const void* __restrict__ bn,
                                                     const int* __restrict__ flag,
                                                     float* __restrict__ out) {
    int i = blockIdx.x * 256 + threadIdx.x;
    if (i < NN) out[(size_t)NB * 256 + i] = (float)IDX(bn, i, *flag);
}

__global__ __launch_bounds__(256) void k_fill(float* __restrict__ p, int n, float v) {
    int i = blockIdx.x * 256 + threadIdx.x;
    if (i < n) p[i] = v;
}

extern "C" void kernel_launch(void* const* d_in, const int* in_sizes, int n_in,
                              void* d_out, int out_size, void* d_ws, size_t ws_size,
                              hipStream_t stream) {
    const float* h_node = (const float*)d_in[0];
    const float* pos    = (const float*)d_in[1];
    const float* h_edge = (const float*)d_in[2];
    const float* W_node = (const float*)d_in[3];
    const float* W_edge = (const float*)d_in[4];
    const float* W_eu   = (const float*)d_in[5];
    const float* b_eu   = (const float*)d_in[6];
    const float* W_msg  = (const float*)d_in[7];
    const float* b_msg  = (const float*)d_in[8];
    const float* W_nu   = (const float*)d_in[9];
    const float* b_nu   = (const float*)d_in[10];
    const float* Wf1    = (const float*)d_in[11];
    const float* bf1    = (const float*)d_in[12];
    const float* Wf2    = (const float*)d_in[13];
    const float* bf2    = (const float*)d_in[14];
    const void* ei = d_in[15];
    const void* bn = d_in[16];
    const void* be = d_in[17];

    float* out = (float*)d_out;

    const size_t SZ_FLAG = 256;
    const size_t SZ_HN   = (size_t)NN * 256;
    const size_t SZ_HE   = (size_t)NE * 128;
    const size_t SZ_AGG  = (size_t)NN * 256 * 2;
    const size_t SZ_R    = (size_t)NN * 512;
    const size_t SZ_PERM = (size_t)NE * 4;
    const size_t SZ_INV  = (size_t)NE * 4;
    const size_t SZ_SRC  = (size_t)NE * 4;
    const size_t SZ_DST  = (size_t)NE * 4;
    const size_t SZ_DS   = (size_t)NE * 4;
    const size_t SZ_PTR  = 512 * 1024;
    const size_t SZ_CUR  = 512 * 1024;
    const size_t SZ_W1   = (size_t)3 * 128 * 128;
    const size_t SZ_W2   = (size_t)3 * 256 * 128;
    const size_t SZ_WNU  = (size_t)3 * 256 * 512;
    const size_t SZ_WPRE = (size_t)3 * 512 * 256;
    const size_t SZ_POOL = (size_t)NB * 384 * 2;
    const size_t SZ_WF1  = (size_t)512 * 384;
    const size_t SZ_WF2  = (size_t)256 * 512;
    const size_t NEED = SZ_FLAG + SZ_HN + SZ_HE + SZ_AGG + SZ_R + SZ_PERM +
                        SZ_INV + SZ_SRC + SZ_DST + SZ_DS + SZ_PTR + SZ_CUR +
                        SZ_W1 + SZ_W2 + SZ_WNU + SZ_WPRE + SZ_POOL + SZ_WF1 +
                        SZ_WF2;  // ~227 MB

    char* ws = (char*)d_ws;
    int* flag = (int*)ws;                       ws += SZ_FLAG;
    unsigned char* hn8 = (unsigned char*)ws;    ws += SZ_HN;
    unsigned char* he8 = (unsigned char*)ws;    ws += SZ_HE;
    unsigned short* agg = (unsigned short*)ws;  ws += SZ_AGG;
    unsigned char* R = (unsigned char*)ws;      ws += SZ_R;
    int* perm = (int*)ws;                       ws += SZ_PERM;
    int* inv = (int*)ws;                        ws += SZ_INV;
    int* srcs = (int*)ws;                       ws += SZ_SRC;
    int* dsts = (int*)ws;                       ws += SZ_DST;
    float* dist_s = (float*)ws;                 ws += SZ_DS;
    int* rowptr = (int*)ws;                     ws += SZ_PTR;
    int* cursor = (int*)ws;                     ws += SZ_CUR;
    unsigned char* W1T = (unsigned char*)ws;    ws += SZ_W1;
    unsigned char* W2T = (unsigned char*)ws;    ws += SZ_W2;
    unsigned char* WnuT = (unsigned char*)ws;   ws += SZ_WNU;
    unsigned char* WpreT = (unsigned char*)ws;  ws += SZ_WPRE;
    unsigned short* pooled = (unsigned short*)ws; ws += SZ_POOL;
    unsigned char* Wf1T = (unsigned char*)ws;   ws += SZ_WF1;
    unsigned char* Wf2T = (unsigned char*)ws;   ws += SZ_WF2;

    if (ws_size < NEED) {
        float enc = -(100000.0f + (float)(ws_size >> 20));
        k_detect<<<1, 64, 0, stream>>>((const int*)bn, flag);
        k_fill<<<(NB * 256 + 255) / 256, 256, 0, stream>>>(out, NB * 256, enc);
        k_write_batch<<<(NN + 255) / 256, 256, 0, stream>>>(bn, flag, out);
        return;
    }

    k_detect<<<1, 64, 0, stream>>>((const int*)bn, flag);
    k_tr_w1<<<(3 * 128 * 128 + 255) / 256, 256, 0, stream>>>(W_eu, W1T);
    k_tr_w2<<<(3 * 256 * 128 + 255) / 256, 256, 0, stream>>>(W_msg, W2T);
    k_tr_nu<<<(3 * 256 * 512 + 255) / 256, 256, 0, stream>>>(W_nu, WnuT);
    k_tr_pre<<<(3 * 512 * 256 + 255) / 256, 256, 0, stream>>>(W_eu, W_msg, WpreT);
    k_tr_f1<<<(512 * 384 + 255) / 256, 256, 0, stream>>>(Wf1, Wf1T);
    k_tr_f2<<<(256 * 512 + 255) / 256, 256, 0, stream>>>(Wf2, Wf2T);
    k_node_embed<<<NN / 8, 256, 0, stream>>>(h_node, W_node, hn8);

    hipMemsetAsync(cursor, 0, (size_t)NN * 4, stream);
    k_hist<<<(NE + 255) / 256, 256, 0, stream>>>(ei, flag, cursor);
    k_scan<<<1, 1024, 0, stream>>>(cursor, rowptr);
    hipMemcpyAsync(cursor, rowptr, (size_t)NN * 4, hipMemcpyDeviceToDevice, stream);
    k_perm<<<(NE + 255) / 256, 256, 0, stream>>>(ei, flag, pos, cursor, perm,
                                                 inv, srcs, dsts, dist_s);
    k_edge_embed<<<NE / 16, 256, 0, stream>>>(h_edge, W_edge, perm, he8);

    k_node_pre<<<(NN + 63) / 64, 256, 0, stream>>>(hn8, WpreT, R);

    for (int l = 0; l < 3; ++l) {
        hipMemsetAsync(agg, 0, SZ_AGG, stream);
        k_edge_fused<<<NE / 32, 256, 0, stream>>>(
            he8, R, dist_s, srcs, dsts,
            W1T + (size_t)l * 128 * 128, W_eu + (size_t)l * 641 * 128,
            b_eu + (size_t)l * 128,
            W2T + (size_t)l * 256 * 128, b_msg + (size_t)l * 256, agg);
        int do_pre = (l < 2) ? 1 : 0;
        const unsigned char* wpre_next = WpreT + (size_t)(do_pre ? (l + 1) : 0) * 512 * 256;
        k_node_fused<<<(NN + 63) / 64, 256, 0, stream>>>(
            hn8, agg, WnuT + (size_t)l * 256 * 512, b_nu + (size_t)l * 256,
            wpre_next, R, do_pre);
    }

    k_pool_means<<<NB, 512, 0, stream>>>(hn8, he8, inv, bn, be, flag, pooled);
    k_final<<<(NB + 63) / 64, 256, 0, stream>>>(pooled, Wf1T, bf1, Wf2T, bf2, out);
    k_write_batch<<<(NN + 255) / 256, 256, 0, stream>>>(bn, flag, out);
}